// Round 1
// baseline (1122.564 us; speedup 1.0000x reference)
//
#include <hip/hip_runtime.h>
#include <hip/hip_bf16.h>
#include <stdint.h>

#define EPS 1e-5f

// ---------------- edge dtype detection ----------------
// If edge_index is int64 (little-endian, values < 2^31), every odd 32-bit word
// is zero. With int32 data those words are random node indices (~0 chance all 0).
__global__ void k_detect(const uint32_t* __restrict__ e, int* __restrict__ flag) {
    if (threadIdx.x == 0 && blockIdx.x == 0) {
        int is64 = 1;
        for (int i = 1; i < 256; i += 2)
            if (e[i] != 0u) { is64 = 0; break; }
        *flag = is64;
    }
}

__global__ void k_convert(const void* __restrict__ eidx, const int* __restrict__ flag,
                          int* __restrict__ src, int* __restrict__ dst, int E) {
    int e = blockIdx.x * blockDim.x + threadIdx.x;
    if (e >= E) return;
    if (*flag) {
        const long long* p = (const long long*)eidx;
        src[e] = (int)p[e];
        dst[e] = (int)p[(size_t)E + e];
    } else {
        const int* p = (const int*)eidx;
        src[e] = p[e];
        dst[e] = p[(size_t)E + e];
    }
}

// ---------------- degree count ----------------
__global__ void k_count(const int* __restrict__ dst, int* __restrict__ cnt, int E) {
    int e = blockIdx.x * blockDim.x + threadIdx.x;
    if (e < E) atomicAdd(&cnt[dst[e]], 1);
}

// ---------------- exclusive scan (3 kernels) ----------------
#define SCAN_CHUNK 2048   // 256 threads * 8
__global__ void k_scan1(const int* __restrict__ cnt, int* __restrict__ outp,
                        int* __restrict__ bsums, int N) {
    __shared__ int sm[256];
    int t = threadIdx.x;
    int base = blockIdx.x * SCAN_CHUNK + t * 8;
    int v[8];
    int s = 0;
    #pragma unroll
    for (int i = 0; i < 8; i++) {
        int idx = base + i;
        int x = (idx < N) ? cnt[idx] : 0;
        v[i] = s;  // exclusive within thread
        s += x;
    }
    sm[t] = s;
    __syncthreads();
    for (int off = 1; off < 256; off <<= 1) {
        int tv = (t >= off) ? sm[t - off] : 0;
        __syncthreads();
        sm[t] += tv;
        __syncthreads();
    }
    int texcl = (t == 0) ? 0 : sm[t - 1];
    #pragma unroll
    for (int i = 0; i < 8; i++) {
        int idx = base + i;
        if (idx < N) outp[idx] = v[i] + texcl;
    }
    if (t == 255) bsums[blockIdx.x] = sm[255];
}

__global__ void k_scan2(int* __restrict__ bsums, int nb) {
    if (threadIdx.x == 0 && blockIdx.x == 0) {
        int s = 0;
        for (int i = 0; i < nb; i++) { int x = bsums[i]; bsums[i] = s; s += x; }
    }
}

__global__ void k_scan3(int* __restrict__ rowptr, const int* __restrict__ bsums, int N) {
    int i = blockIdx.x * blockDim.x + threadIdx.x;
    if (i < N) rowptr[i] += bsums[i / SCAN_CHUNK];
}

// ---------------- prep: cursor copy, dinv, rowptr[N] ----------------
__global__ void k_prep(const int* __restrict__ cnt, int* __restrict__ rowptr,
                       int* __restrict__ cursor, float* __restrict__ dinv, int N, int E) {
    int v = blockIdx.x * blockDim.x + threadIdx.x;
    if (v < N) {
        cursor[v] = rowptr[v];
        dinv[v] = rsqrtf((float)(cnt[v] + 1));  // +1 self loop; always > 0
    }
    if (v == 0) rowptr[N] = E;
}

// ---------------- CSR fill ----------------
__global__ void k_fill(const int* __restrict__ src, const int* __restrict__ dst,
                       int* __restrict__ cursor, int* __restrict__ adj, int E) {
    int e = blockIdx.x * blockDim.x + threadIdx.x;
    if (e < E) {
        int pos = atomicAdd(&cursor[dst[e]], 1);
        adj[pos] = src[e];
    }
}

// ---------------- GEMM: C[N x OUTC] = A[N x 128] * W[128 x OUTC] ----------------
template <int OUTC>
__global__ __launch_bounds__(256) void k_gemm(const float* __restrict__ A,
                                              const float* __restrict__ W,
                                              float* __restrict__ C, int N) {
    constexpr int K = 128;
    constexpr int TPR = OUTC / 4;   // threads covering one row's columns
    constexpr int RG = 256 / TPR;   // row groups per block
    constexpr int R = 32 / RG;      // rows per thread
    __shared__ float Wl[K * OUTC];
    __shared__ float Al[32 * K];
    int t = threadIdx.x;
    // stage W (coalesced float4)
    for (int i = t; i < K * OUTC / 4; i += 256)
        ((float4*)Wl)[i] = ((const float4*)W)[i];
    int rowTile = blockIdx.x * 32;
    size_t abase4 = (size_t)rowTile * K / 4;
    size_t total4 = (size_t)N * K / 4;
    for (int i = t; i < 32 * K / 4; i += 256) {
        size_t idx4 = abase4 + i;
        float4 val = (idx4 < total4) ? ((const float4*)A)[idx4] : make_float4(0, 0, 0, 0);
        ((float4*)Al)[i] = val;
    }
    __syncthreads();

    int c0 = (t % TPR) * 4;
    int rbase = (t / TPR) * R;
    float4 acc[R];
    #pragma unroll
    for (int r = 0; r < R; r++) acc[r] = make_float4(0, 0, 0, 0);

    for (int k = 0; k < K; k += 4) {
        float4 w0 = *(const float4*)&Wl[(k + 0) * OUTC + c0];
        float4 w1 = *(const float4*)&Wl[(k + 1) * OUTC + c0];
        float4 w2 = *(const float4*)&Wl[(k + 2) * OUTC + c0];
        float4 w3 = *(const float4*)&Wl[(k + 3) * OUTC + c0];
        #pragma unroll
        for (int r = 0; r < R; r++) {
            float4 a = *(const float4*)&Al[(rbase + r) * K + k];
            acc[r].x += a.x * w0.x + a.y * w1.x + a.z * w2.x + a.w * w3.x;
            acc[r].y += a.x * w0.y + a.y * w1.y + a.z * w2.y + a.w * w3.y;
            acc[r].z += a.x * w0.z + a.y * w1.z + a.z * w2.z + a.w * w3.z;
            acc[r].w += a.x * w0.w + a.y * w1.w + a.z * w2.w + a.w * w3.w;
        }
    }
    #pragma unroll
    for (int r = 0; r < R; r++) {
        int row = rowTile + rbase + r;
        if (row < N) *(float4*)&C[(size_t)row * OUTC + c0] = acc[r];
    }
}

// ---------------- aggregation + LayerNorm + ReLU (layers 0,1; 128 cols) ----------------
__global__ __launch_bounds__(256) void k_agg_ln(const float* __restrict__ h,
                                                const int* __restrict__ rowptr,
                                                const int* __restrict__ adj,
                                                const float* __restrict__ dinv,
                                                const float* __restrict__ bias,
                                                const float* __restrict__ g,
                                                const float* __restrict__ bn,
                                                float* __restrict__ out, int N) {
    int wave = threadIdx.x >> 6;
    int lane = threadIdx.x & 63;
    int v = blockIdx.x * 4 + wave;
    if (v >= N) return;
    float dv = dinv[v];
    int c = lane * 2;
    float2 hv = *(const float2*)&h[(size_t)v * 128 + c];
    float2 bb = *(const float2*)&bias[c];
    float cs = dv * dv;
    float ax = bb.x + cs * hv.x;
    float ay = bb.y + cs * hv.y;
    int e0 = rowptr[v], e1 = rowptr[v + 1];
    for (int e = e0; e < e1; e++) {
        int u = adj[e];
        float cf = dinv[u] * dv;
        float2 hu = *(const float2*)&h[(size_t)u * 128 + c];
        ax += cf * hu.x;
        ay += cf * hu.y;
    }
    // LayerNorm over 128 features (64-lane wave reduction)
    float s = ax + ay;
    #pragma unroll
    for (int m = 32; m >= 1; m >>= 1) s += __shfl_xor(s, m);
    float mu = s * (1.0f / 128.0f);
    float dx = ax - mu, dy = ay - mu;
    float vs = dx * dx + dy * dy;
    #pragma unroll
    for (int m = 32; m >= 1; m >>= 1) vs += __shfl_xor(vs, m);
    float rs = rsqrtf(vs * (1.0f / 128.0f) + EPS);
    float2 gg = *(const float2*)&g[c];
    float2 bnv = *(const float2*)&bn[c];
    float ox = dx * rs * gg.x + bnv.x;
    float oy = dy * rs * gg.y + bnv.y;
    ox = fmaxf(ox, 0.0f);
    oy = fmaxf(oy, 0.0f);
    *(float2*)&out[(size_t)v * 128 + c] = make_float2(ox, oy);
}

// ---------------- aggregation + bias (layer 2; 64 cols) ----------------
__global__ __launch_bounds__(256) void k_agg_out(const float* __restrict__ h,
                                                 const int* __restrict__ rowptr,
                                                 const int* __restrict__ adj,
                                                 const float* __restrict__ dinv,
                                                 const float* __restrict__ bias,
                                                 float* __restrict__ out, int N) {
    int wave = threadIdx.x >> 6;
    int lane = threadIdx.x & 63;
    int v = blockIdx.x * 4 + wave;
    if (v >= N) return;
    float dv = dinv[v];
    float acc = bias[lane] + dv * dv * h[(size_t)v * 64 + lane];
    int e0 = rowptr[v], e1 = rowptr[v + 1];
    for (int e = e0; e < e1; e++) {
        int u = adj[e];
        acc += dinv[u] * dv * h[(size_t)u * 64 + lane];
    }
    out[(size_t)v * 64 + lane] = acc;
}

extern "C" void kernel_launch(void* const* d_in, const int* in_sizes, int n_in,
                              void* d_out, int out_size, void* d_ws, size_t ws_size,
                              hipStream_t stream) {
    const float* x   = (const float*)d_in[0];
    const void*  eidx = d_in[1];
    const float* W0 = (const float*)d_in[2];
    const float* b0 = (const float*)d_in[3];
    const float* W1 = (const float*)d_in[4];
    const float* b1 = (const float*)d_in[5];
    const float* W2 = (const float*)d_in[6];
    const float* b2 = (const float*)d_in[7];
    const float* g0 = (const float*)d_in[8];
    const float* bn0 = (const float*)d_in[9];
    const float* g1 = (const float*)d_in[10];
    const float* bn1 = (const float*)d_in[11];

    int N = in_sizes[0] / 128;
    int E = in_sizes[1] / 2;

    char* p = (char*)d_ws;
    auto alloc = [&](size_t bytes) {
        char* r = p;
        p += (bytes + 255) & ~(size_t)255;
        return r;
    };
    int*   flag   = (int*)alloc(4);
    int*   src32  = (int*)alloc((size_t)E * 4);
    int*   dst32  = (int*)alloc((size_t)E * 4);
    int*   cnt    = (int*)alloc((size_t)N * 4);
    int*   rowptr = (int*)alloc(((size_t)N + 1) * 4);
    int*   cursor = (int*)alloc((size_t)N * 4);
    float* dinv   = (float*)alloc((size_t)N * 4);
    int*   adj    = (int*)alloc((size_t)E * 4);
    int*   bsums  = (int*)alloc(1024);
    float* bufA   = (float*)alloc((size_t)N * 128 * 4);
    float* bufB   = (float*)alloc((size_t)N * 128 * 4);

    int eb = (E + 255) / 256;
    int nb = (N + 255) / 256;
    int nscan = (N + SCAN_CHUNK - 1) / SCAN_CHUNK;

    k_detect<<<1, 64, 0, stream>>>((const uint32_t*)eidx, flag);
    k_convert<<<eb, 256, 0, stream>>>(eidx, flag, src32, dst32, E);
    hipMemsetAsync(cnt, 0, (size_t)N * 4, stream);
    k_count<<<eb, 256, 0, stream>>>(dst32, cnt, E);
    k_scan1<<<nscan, 256, 0, stream>>>(cnt, rowptr, bsums, N);
    k_scan2<<<1, 64, 0, stream>>>(bsums, nscan);
    k_scan3<<<nb, 256, 0, stream>>>(rowptr, bsums, N);
    k_prep<<<nb, 256, 0, stream>>>(cnt, rowptr, cursor, dinv, N, E);
    k_fill<<<eb, 256, 0, stream>>>(src32, dst32, cursor, adj, E);

    int gemmb = (N + 31) / 32;
    int aggb = (N + 3) / 4;

    // layer 0: x @ W0 -> bufA; agg+LN+ReLU -> bufB
    k_gemm<128><<<gemmb, 256, 0, stream>>>(x, W0, bufA, N);
    k_agg_ln<<<aggb, 256, 0, stream>>>(bufA, rowptr, adj, dinv, b0, g0, bn0, bufB, N);
    // layer 1: bufB @ W1 -> bufA; agg+LN+ReLU -> bufB
    k_gemm<128><<<gemmb, 256, 0, stream>>>(bufB, W1, bufA, N);
    k_agg_ln<<<aggb, 256, 0, stream>>>(bufA, rowptr, adj, dinv, b1, g1, bn1, bufB, N);
    // layer 2: bufB @ W2 -> bufA (N x 64); agg+bias -> d_out
    k_gemm<64><<<gemmb, 256, 0, stream>>>(bufB, W2, bufA, N);
    k_agg_out<<<aggb, 256, 0, stream>>>(bufA, rowptr, adj, dinv, b2, (float*)d_out, N);
}

// Round 2
// 547.498 us; speedup vs baseline: 2.0504x; 2.0504x over previous
//
#include <hip/hip_runtime.h>
#include <hip/hip_bf16.h>
#include <stdint.h>

#define EPS 1e-5f

// ---------------- edge dtype detection ----------------
__global__ void k_detect(const uint32_t* __restrict__ e, int* __restrict__ flag) {
    if (threadIdx.x == 0 && blockIdx.x == 0) {
        int is64 = 1;
        for (int i = 1; i < 256; i += 2)
            if (e[i] != 0u) { is64 = 0; break; }
        *flag = is64;
    }
}

// ---------------- convert + degree count (fused) ----------------
__global__ void k_convert_count(const void* __restrict__ eidx, const int* __restrict__ flag,
                                int* __restrict__ src, int* __restrict__ dst,
                                int* __restrict__ cnt, int E) {
    int e = blockIdx.x * blockDim.x + threadIdx.x;
    if (e >= E) return;
    int s, d;
    if (*flag) {
        const long long* p = (const long long*)eidx;
        s = (int)p[e];
        d = (int)p[(size_t)E + e];
    } else {
        const int* p = (const int*)eidx;
        s = p[e];
        d = p[(size_t)E + e];
    }
    src[e] = s;
    dst[e] = d;
    atomicAdd(&cnt[d], 1);
}

// ---------------- exclusive scan ----------------
#define SCAN_CHUNK 2048
__global__ void k_scan1(const int* __restrict__ cnt, int* __restrict__ outp,
                        int* __restrict__ bsums, int N) {
    __shared__ int sm[256];
    int t = threadIdx.x;
    int base = blockIdx.x * SCAN_CHUNK + t * 8;
    int v[8];
    int s = 0;
    #pragma unroll
    for (int i = 0; i < 8; i++) {
        int idx = base + i;
        int x = (idx < N) ? cnt[idx] : 0;
        v[i] = s;
        s += x;
    }
    sm[t] = s;
    __syncthreads();
    for (int off = 1; off < 256; off <<= 1) {
        int tv = (t >= off) ? sm[t - off] : 0;
        __syncthreads();
        sm[t] += tv;
        __syncthreads();
    }
    int texcl = (t == 0) ? 0 : sm[t - 1];
    #pragma unroll
    for (int i = 0; i < 8; i++) {
        int idx = base + i;
        if (idx < N) outp[idx] = v[i] + texcl;
    }
    if (t == 255) bsums[blockIdx.x] = sm[255];
}

__global__ void k_scan2(int* __restrict__ bsums, int nb) {
    if (threadIdx.x == 0 && blockIdx.x == 0) {
        int s = 0;
        for (int i = 0; i < nb; i++) { int x = bsums[i]; bsums[i] = s; s += x; }
    }
}

// ---------------- scan3 + prep (fused): finalize rowptr, cursor, dinv ----------------
__global__ void k_scan3_prep(int* __restrict__ rowptr, const int* __restrict__ bsums,
                             const int* __restrict__ cnt, int* __restrict__ cursor,
                             float* __restrict__ dinv, int N, int E) {
    int i = blockIdx.x * blockDim.x + threadIdx.x;
    if (i < N) {
        int rp = rowptr[i] + bsums[i / SCAN_CHUNK];
        rowptr[i] = rp;
        cursor[i] = rp;
        dinv[i] = rsqrtf((float)(cnt[i] + 1));   // +1 self loop, always > 0
    }
    if (i == 0) rowptr[N] = E;
}

// ---------------- CSR fill (adj + precomputed coef) ----------------
__global__ void k_fill(const int* __restrict__ src, const int* __restrict__ dst,
                       int* __restrict__ cursor, int* __restrict__ adj,
                       float* __restrict__ coef, const float* __restrict__ dinv, int E) {
    int e = blockIdx.x * blockDim.x + threadIdx.x;
    if (e < E) {
        int s = src[e], d = dst[e];
        int pos = atomicAdd(&cursor[d], 1);
        adj[pos] = s;
        coef[pos] = dinv[s] * dinv[d];
    }
}

// ---------------- GEMM: C[N x OUTC] = A[N x 128] * W[128 x OUTC] ----------------
// 64-row tile, A staged in LDS (stride 132 to break bank aliasing), W via L1/L2.
template <int OUTC>
__global__ __launch_bounds__(256) void k_gemm(const float* __restrict__ A,
                                              const float* __restrict__ W,
                                              float* __restrict__ C, int N) {
    constexpr int K = 128;
    constexpr int LDA = 132;
    constexpr int CPT = 8;            // cols per thread
    constexpr int TPR = OUTC / CPT;   // threads per row
    constexpr int RG = 256 / TPR;     // row groups
    constexpr int R = 64 / RG;        // rows per thread
    __shared__ float Al[64 * LDA];
    int t = threadIdx.x;
    int rowTile = blockIdx.x * 64;

    for (int i = t; i < 64 * 32; i += 256) {
        int r = i >> 5, c4 = i & 31;
        int row = rowTile + r;
        float4 val = make_float4(0.f, 0.f, 0.f, 0.f);
        if (row < N) val = ((const float4*)A)[(size_t)row * 32 + c4];
        *(float4*)&Al[r * LDA + c4 * 4] = val;
    }
    __syncthreads();

    int c0 = (t % TPR) * CPT;
    int rbase = (t / TPR) * R;
    const float* arow = &Al[rbase * LDA];

    float4 acc0[R], acc1[R];
    #pragma unroll
    for (int r = 0; r < R; r++) {
        acc0[r] = make_float4(0.f, 0.f, 0.f, 0.f);
        acc1[r] = make_float4(0.f, 0.f, 0.f, 0.f);
    }

    #pragma unroll 2
    for (int k = 0; k < K; k++) {
        float4 w0 = *(const float4*)&W[k * OUTC + c0];
        float4 w1 = *(const float4*)&W[k * OUTC + c0 + 4];
        #pragma unroll
        for (int r = 0; r < R; r++) {
            float a = arow[r * LDA + k];
            acc0[r].x += a * w0.x; acc0[r].y += a * w0.y;
            acc0[r].z += a * w0.z; acc0[r].w += a * w0.w;
            acc1[r].x += a * w1.x; acc1[r].y += a * w1.y;
            acc1[r].z += a * w1.z; acc1[r].w += a * w1.w;
        }
    }

    #pragma unroll
    for (int r = 0; r < R; r++) {
        int row = rowTile + rbase + r;
        if (row < N) {
            *(float4*)&C[(size_t)row * OUTC + c0] = acc0[r];
            *(float4*)&C[(size_t)row * OUTC + c0 + 4] = acc1[r];
        }
    }
}

// ---------------- aggregation + LayerNorm + ReLU (128 cols, 1 wave/node) ----------------
__global__ __launch_bounds__(256) void k_agg_ln(const float* __restrict__ h,
                                                const int* __restrict__ rowptr,
                                                const int* __restrict__ adj,
                                                const float* __restrict__ coef,
                                                const float* __restrict__ dinv,
                                                const float* __restrict__ bias,
                                                const float* __restrict__ g,
                                                const float* __restrict__ bn,
                                                float* __restrict__ out, int N) {
    int wave = threadIdx.x >> 6;
    int lane = threadIdx.x & 63;
    int v = blockIdx.x * 4 + wave;
    if (v >= N) return;
    int c = lane * 2;
    float dv = dinv[v];
    float2 hv = *(const float2*)&h[(size_t)v * 128 + c];
    float2 bb = *(const float2*)&bias[c];
    float cs = dv * dv;
    float ax = bb.x + cs * hv.x;
    float ay = bb.y + cs * hv.y;
    int e0 = rowptr[v], e1 = rowptr[v + 1];
    int e = e0;
    for (; e + 4 <= e1; e += 4) {
        int u0 = adj[e], u1 = adj[e + 1], u2 = adj[e + 2], u3 = adj[e + 3];
        float c0f = coef[e], c1f = coef[e + 1], c2f = coef[e + 2], c3f = coef[e + 3];
        float2 h0 = *(const float2*)&h[(size_t)u0 * 128 + c];
        float2 h1 = *(const float2*)&h[(size_t)u1 * 128 + c];
        float2 h2 = *(const float2*)&h[(size_t)u2 * 128 + c];
        float2 h3 = *(const float2*)&h[(size_t)u3 * 128 + c];
        ax += c0f * h0.x + c1f * h1.x + c2f * h2.x + c3f * h3.x;
        ay += c0f * h0.y + c1f * h1.y + c2f * h2.y + c3f * h3.y;
    }
    for (; e < e1; e++) {
        int u = adj[e];
        float cf = coef[e];
        float2 hu = *(const float2*)&h[(size_t)u * 128 + c];
        ax += cf * hu.x;
        ay += cf * hu.y;
    }
    // LayerNorm over 128 features
    float s = ax + ay;
    #pragma unroll
    for (int m = 32; m >= 1; m >>= 1) s += __shfl_xor(s, m);
    float mu = s * (1.0f / 128.0f);
    float dx = ax - mu, dy = ay - mu;
    float vs = dx * dx + dy * dy;
    #pragma unroll
    for (int m = 32; m >= 1; m >>= 1) vs += __shfl_xor(vs, m);
    float rs = rsqrtf(vs * (1.0f / 128.0f) + EPS);
    float2 gg = *(const float2*)&g[c];
    float2 bnv = *(const float2*)&bn[c];
    float ox = fmaxf(dx * rs * gg.x + bnv.x, 0.0f);
    float oy = fmaxf(dy * rs * gg.y + bnv.y, 0.0f);
    *(float2*)&out[(size_t)v * 128 + c] = make_float2(ox, oy);
}

// ---------------- aggregation + bias (64 cols, 1 wave/node) ----------------
__global__ __launch_bounds__(256) void k_agg_out(const float* __restrict__ h,
                                                 const int* __restrict__ rowptr,
                                                 const int* __restrict__ adj,
                                                 const float* __restrict__ coef,
                                                 const float* __restrict__ dinv,
                                                 const float* __restrict__ bias,
                                                 float* __restrict__ out, int N) {
    int wave = threadIdx.x >> 6;
    int lane = threadIdx.x & 63;
    int v = blockIdx.x * 4 + wave;
    if (v >= N) return;
    float dv = dinv[v];
    float acc = bias[lane] + dv * dv * h[(size_t)v * 64 + lane];
    int e0 = rowptr[v], e1 = rowptr[v + 1];
    int e = e0;
    for (; e + 4 <= e1; e += 4) {
        int u0 = adj[e], u1 = adj[e + 1], u2 = adj[e + 2], u3 = adj[e + 3];
        float c0f = coef[e], c1f = coef[e + 1], c2f = coef[e + 2], c3f = coef[e + 3];
        float h0 = h[(size_t)u0 * 64 + lane];
        float h1 = h[(size_t)u1 * 64 + lane];
        float h2 = h[(size_t)u2 * 64 + lane];
        float h3 = h[(size_t)u3 * 64 + lane];
        acc += c0f * h0 + c1f * h1 + c2f * h2 + c3f * h3;
    }
    for (; e < e1; e++) {
        acc += coef[e] * h[(size_t)adj[e] * 64 + lane];
    }
    out[(size_t)v * 64 + lane] = acc;
}

extern "C" void kernel_launch(void* const* d_in, const int* in_sizes, int n_in,
                              void* d_out, int out_size, void* d_ws, size_t ws_size,
                              hipStream_t stream) {
    const float* x    = (const float*)d_in[0];
    const void*  eidx = d_in[1];
    const float* W0 = (const float*)d_in[2];
    const float* b0 = (const float*)d_in[3];
    const float* W1 = (const float*)d_in[4];
    const float* b1 = (const float*)d_in[5];
    const float* W2 = (const float*)d_in[6];
    const float* b2 = (const float*)d_in[7];
    const float* g0 = (const float*)d_in[8];
    const float* bn0 = (const float*)d_in[9];
    const float* g1 = (const float*)d_in[10];
    const float* bn1 = (const float*)d_in[11];

    int N = in_sizes[0] / 128;
    int E = in_sizes[1] / 2;

    char* p = (char*)d_ws;
    auto alloc = [&](size_t bytes) {
        char* r = p;
        p += (bytes + 255) & ~(size_t)255;
        return r;
    };
    int*   flag   = (int*)alloc(4);
    int*   src32  = (int*)alloc((size_t)E * 4);
    int*   dst32  = (int*)alloc((size_t)E * 4);
    int*   cnt    = (int*)alloc((size_t)N * 4);
    int*   rowptr = (int*)alloc(((size_t)N + 1) * 4);
    int*   cursor = (int*)alloc((size_t)N * 4);
    float* dinv   = (float*)alloc((size_t)N * 4);
    int*   adj    = (int*)alloc((size_t)E * 4);
    float* coef   = (float*)alloc((size_t)E * 4);
    int*   bsums  = (int*)alloc(4096);
    float* bufA   = (float*)alloc((size_t)N * 128 * 4);
    float* bufB   = (float*)alloc((size_t)N * 128 * 4);

    int eb = (E + 255) / 256;
    int nb = (N + 255) / 256;
    int nscan = (N + SCAN_CHUNK - 1) / SCAN_CHUNK;

    k_detect<<<1, 64, 0, stream>>>((const uint32_t*)eidx, flag);
    hipMemsetAsync(cnt, 0, (size_t)N * 4, stream);
    k_convert_count<<<eb, 256, 0, stream>>>(eidx, flag, src32, dst32, cnt, E);
    k_scan1<<<nscan, 256, 0, stream>>>(cnt, rowptr, bsums, N);
    k_scan2<<<1, 64, 0, stream>>>(bsums, nscan);
    k_scan3_prep<<<nb, 256, 0, stream>>>(rowptr, bsums, cnt, cursor, dinv, N, E);
    k_fill<<<eb, 256, 0, stream>>>(src32, dst32, cursor, adj, coef, dinv, E);

    int gemmb = (N + 63) / 64;
    int aggb = (N + 3) / 4;

    k_gemm<128><<<gemmb, 256, 0, stream>>>(x, W0, bufA, N);
    k_agg_ln<<<aggb, 256, 0, stream>>>(bufA, rowptr, adj, coef, dinv, b0, g0, bn0, bufB, N);
    k_gemm<128><<<gemmb, 256, 0, stream>>>(bufB, W1, bufA, N);
    k_agg_ln<<<aggb, 256, 0, stream>>>(bufA, rowptr, adj, coef, dinv, b1, g1, bn1, bufB, N);
    k_gemm<64><<<gemmb, 256, 0, stream>>>(bufB, W2, bufA, N);
    k_agg_out<<<aggb, 256, 0, stream>>>(bufA, rowptr, adj, coef, dinv, b2, (float*)d_out, N);
}

// Round 3
// 419.858 us; speedup vs baseline: 2.6737x; 1.3040x over previous
//
#include <hip/hip_runtime.h>
#include <hip/hip_bf16.h>
#include <stdint.h>

#define EPS 1e-5f
#define KPAD 136   // 128 k + 8 pad (bf16 elems) -> 272B row stride, 16B aligned

typedef __attribute__((ext_vector_type(8))) __bf16 bf16x8;
typedef __attribute__((ext_vector_type(4))) float f32x4;

// ---------------- edge dtype detection ----------------
__global__ void k_detect(const uint32_t* __restrict__ e, int* __restrict__ flag) {
    if (threadIdx.x == 0 && blockIdx.x == 0) {
        int is64 = 1;
        for (int i = 1; i < 256; i += 2)
            if (e[i] != 0u) { is64 = 0; break; }
        *flag = is64;
    }
}

// ---------------- convert + degree count (fused) ----------------
__global__ void k_convert_count(const void* __restrict__ eidx, const int* __restrict__ flag,
                                int* __restrict__ src, int* __restrict__ dst,
                                int* __restrict__ cnt, int E) {
    int e = blockIdx.x * blockDim.x + threadIdx.x;
    if (e >= E) return;
    int s, d;
    if (*flag) {
        const long long* p = (const long long*)eidx;
        s = (int)p[e];
        d = (int)p[(size_t)E + e];
    } else {
        const int* p = (const int*)eidx;
        s = p[e];
        d = p[(size_t)E + e];
    }
    src[e] = s;
    dst[e] = d;
    atomicAdd(&cnt[d], 1);
}

// ---------------- exclusive scan ----------------
#define SCAN_CHUNK 2048
__global__ void k_scan1(const int* __restrict__ cnt, int* __restrict__ outp,
                        int* __restrict__ bsums, int N) {
    __shared__ int sm[256];
    int t = threadIdx.x;
    int base = blockIdx.x * SCAN_CHUNK + t * 8;
    int v[8];
    int s = 0;
    #pragma unroll
    for (int i = 0; i < 8; i++) {
        int idx = base + i;
        int x = (idx < N) ? cnt[idx] : 0;
        v[i] = s;
        s += x;
    }
    sm[t] = s;
    __syncthreads();
    for (int off = 1; off < 256; off <<= 1) {
        int tv = (t >= off) ? sm[t - off] : 0;
        __syncthreads();
        sm[t] += tv;
        __syncthreads();
    }
    int texcl = (t == 0) ? 0 : sm[t - 1];
    #pragma unroll
    for (int i = 0; i < 8; i++) {
        int idx = base + i;
        if (idx < N) outp[idx] = v[i] + texcl;
    }
    if (t == 255) bsums[blockIdx.x] = sm[255];
}

__global__ void k_scan2(int* __restrict__ bsums, int nb) {
    if (threadIdx.x == 0 && blockIdx.x == 0) {
        int s = 0;
        for (int i = 0; i < nb; i++) { int x = bsums[i]; bsums[i] = s; s += x; }
    }
}

__global__ void k_scan3_prep(int* __restrict__ rowptr, const int* __restrict__ bsums,
                             const int* __restrict__ cnt, int* __restrict__ cursor,
                             float* __restrict__ dinv, int N, int E) {
    int i = blockIdx.x * blockDim.x + threadIdx.x;
    if (i < N) {
        int rp = rowptr[i] + bsums[i / SCAN_CHUNK];
        rowptr[i] = rp;
        cursor[i] = rp;
        dinv[i] = rsqrtf((float)(cnt[i] + 1));
    }
    if (i == 0) rowptr[N] = E;
}

__global__ void k_fill(const int* __restrict__ src, const int* __restrict__ dst,
                       int* __restrict__ cursor, int* __restrict__ adj,
                       float* __restrict__ coef, const float* __restrict__ dinv, int E) {
    int e = blockIdx.x * blockDim.x + threadIdx.x;
    if (e < E) {
        int s = src[e], d = dst[e];
        int pos = atomicAdd(&cursor[d], 1);
        adj[pos] = s;
        coef[pos] = dinv[s] * dinv[d];
    }
}

// ---------------- W -> transposed padded bf16 hi/lo ----------------
// T layout: [hi: outc rows x KPAD][lo: outc rows x KPAD], T[c*KPAD + k] = W[k][c]
__global__ void k_wconv(const float* __restrict__ W0, const float* __restrict__ W1,
                        const float* __restrict__ W2, __bf16* __restrict__ T0,
                        __bf16* __restrict__ T1, __bf16* __restrict__ T2) {
    int layer = blockIdx.y;
    const float* W = layer == 0 ? W0 : (layer == 1 ? W1 : W2);
    __bf16* T = layer == 0 ? T0 : (layer == 1 ? T1 : T2);
    int outc = (layer == 2) ? 64 : 128;
    int tid = blockIdx.x * 256 + threadIdx.x;
    if (tid >= 128 * outc) return;
    int k = tid / outc, c = tid % outc;
    float f = W[tid];
    __bf16 hb = (__bf16)f;
    __bf16 lb = (__bf16)(f - (float)hb);
    T[c * KPAD + k] = hb;
    T[outc * KPAD + c * KPAD + k] = lb;
}

// ---------------- MFMA GEMM: C[N x OUTC] = A[N x 128] @ W[128 x OUTC] ----------------
// bf16 hi/lo split (3-MFMA emulation, ~fp32 accuracy). Block = 4 waves x 32 rows.
template <int OUTC>
__global__ __launch_bounds__(256, 2) void k_gemm_mfma(const float* __restrict__ A,
                                                      const __bf16* __restrict__ WT,
                                                      float* __restrict__ C, int N) {
    __shared__ __bf16 lds[2 * OUTC * KPAD];
    const int t = threadIdx.x;
    // stage WT (hi||lo) into LDS in 16B chunks (linear copy)
    const int n16 = (2 * OUTC * KPAD * 2) / 16;
    for (int i = t; i < n16; i += 256)
        ((float4*)lds)[i] = ((const float4*)WT)[i];

    const int lane = t & 63;
    const int wv = t >> 6;
    const int c = lane & 15;
    const int hq = lane >> 4;
    const int rowbase = blockIdx.x * 128 + wv * 32;

    // A fragments: row = lane&15, k = ks*32 + 8*hq + j (contiguous 8)
    bf16x8 ahi[2][4], alo[2][4];
    #pragma unroll
    for (int rt = 0; rt < 2; ++rt) {
        int ar = rowbase + rt * 16 + c;
        if (ar > N - 1) ar = N - 1;
        const float* ap = A + (size_t)ar * 128 + hq * 8;
        #pragma unroll
        for (int ks = 0; ks < 4; ++ks) {
            float4 p = *(const float4*)(ap + ks * 32);
            float4 q = *(const float4*)(ap + ks * 32 + 4);
            float v[8] = {p.x, p.y, p.z, p.w, q.x, q.y, q.z, q.w};
            #pragma unroll
            for (int j = 0; j < 8; ++j) {
                __bf16 hb = (__bf16)v[j];
                ahi[rt][ks][j] = hb;
                alo[rt][ks][j] = (__bf16)(v[j] - (float)hb);
            }
        }
    }
    __syncthreads();

    #pragma unroll
    for (int ct = 0; ct < OUTC / 16; ++ct) {
        const __bf16* bp = &lds[(ct * 16 + c) * KPAD + hq * 8];
        bf16x8 bhi[4], blo[4];
        #pragma unroll
        for (int ks = 0; ks < 4; ++ks) {
            bhi[ks] = *reinterpret_cast<const bf16x8*>(bp + ks * 32);
            blo[ks] = *reinterpret_cast<const bf16x8*>(bp + OUTC * KPAD + ks * 32);
        }
        f32x4 acc0 = {0.f, 0.f, 0.f, 0.f};
        f32x4 acc1 = {0.f, 0.f, 0.f, 0.f};
        #pragma unroll
        for (int ks = 0; ks < 4; ++ks) {
            acc0 = __builtin_amdgcn_mfma_f32_16x16x32_bf16(ahi[0][ks], bhi[ks], acc0, 0, 0, 0);
            acc1 = __builtin_amdgcn_mfma_f32_16x16x32_bf16(ahi[1][ks], bhi[ks], acc1, 0, 0, 0);
            acc0 = __builtin_amdgcn_mfma_f32_16x16x32_bf16(alo[0][ks], bhi[ks], acc0, 0, 0, 0);
            acc1 = __builtin_amdgcn_mfma_f32_16x16x32_bf16(alo[1][ks], bhi[ks], acc1, 0, 0, 0);
            acc0 = __builtin_amdgcn_mfma_f32_16x16x32_bf16(ahi[0][ks], blo[ks], acc0, 0, 0, 0);
            acc1 = __builtin_amdgcn_mfma_f32_16x16x32_bf16(ahi[1][ks], blo[ks], acc1, 0, 0, 0);
        }
        // D layout: col = lane&15, row = 4*(lane>>4) + reg
        const int col = ct * 16 + c;
        #pragma unroll
        for (int rt = 0; rt < 2; ++rt) {
            f32x4 a = rt ? acc1 : acc0;
            int row0 = rowbase + rt * 16 + hq * 4;
            #pragma unroll
            for (int r = 0; r < 4; ++r) {
                int row = row0 + r;
                if (row < N) C[(size_t)row * OUTC + col] = a[r];
            }
        }
    }
}

// ---------------- aggregation + LayerNorm + ReLU (128 cols, 1 wave/node) ----------------
__global__ __launch_bounds__(256) void k_agg_ln(const float* __restrict__ h,
                                                const int* __restrict__ rowptr,
                                                const int* __restrict__ adj,
                                                const float* __restrict__ coef,
                                                const float* __restrict__ dinv,
                                                const float* __restrict__ bias,
                                                const float* __restrict__ g,
                                                const float* __restrict__ bn,
                                                float* __restrict__ out, int N) {
    int wave = threadIdx.x >> 6;
    int lane = threadIdx.x & 63;
    int v = blockIdx.x * 4 + wave;
    if (v >= N) return;
    int c = lane * 2;
    float dv = dinv[v];
    float2 hv = *(const float2*)&h[(size_t)v * 128 + c];
    float2 bb = *(const float2*)&bias[c];
    float cs = dv * dv;
    float ax = bb.x + cs * hv.x;
    float ay = bb.y + cs * hv.y;
    int e0 = rowptr[v], e1 = rowptr[v + 1];
    int e = e0;
    for (; e + 4 <= e1; e += 4) {
        int u0 = adj[e], u1 = adj[e + 1], u2 = adj[e + 2], u3 = adj[e + 3];
        float c0f = coef[e], c1f = coef[e + 1], c2f = coef[e + 2], c3f = coef[e + 3];
        float2 h0 = *(const float2*)&h[(size_t)u0 * 128 + c];
        float2 h1 = *(const float2*)&h[(size_t)u1 * 128 + c];
        float2 h2 = *(const float2*)&h[(size_t)u2 * 128 + c];
        float2 h3 = *(const float2*)&h[(size_t)u3 * 128 + c];
        ax += c0f * h0.x + c1f * h1.x + c2f * h2.x + c3f * h3.x;
        ay += c0f * h0.y + c1f * h1.y + c2f * h2.y + c3f * h3.y;
    }
    for (; e < e1; e++) {
        int u = adj[e];
        float cf = coef[e];
        float2 hu = *(const float2*)&h[(size_t)u * 128 + c];
        ax += cf * hu.x;
        ay += cf * hu.y;
    }
    float s = ax + ay;
    #pragma unroll
    for (int m = 32; m >= 1; m >>= 1) s += __shfl_xor(s, m);
    float mu = s * (1.0f / 128.0f);
    float dx = ax - mu, dy = ay - mu;
    float vs = dx * dx + dy * dy;
    #pragma unroll
    for (int m = 32; m >= 1; m >>= 1) vs += __shfl_xor(vs, m);
    float rs = rsqrtf(vs * (1.0f / 128.0f) + EPS);
    float2 gg = *(const float2*)&g[c];
    float2 bnv = *(const float2*)&bn[c];
    float ox = fmaxf(dx * rs * gg.x + bnv.x, 0.0f);
    float oy = fmaxf(dy * rs * gg.y + bnv.y, 0.0f);
    *(float2*)&out[(size_t)v * 128 + c] = make_float2(ox, oy);
}

// ---------------- aggregation + bias (64 cols, 1 wave/node) ----------------
__global__ __launch_bounds__(256) void k_agg_out(const float* __restrict__ h,
                                                 const int* __restrict__ rowptr,
                                                 const int* __restrict__ adj,
                                                 const float* __restrict__ coef,
                                                 const float* __restrict__ dinv,
                                                 const float* __restrict__ bias,
                                                 float* __restrict__ out, int N) {
    int wave = threadIdx.x >> 6;
    int lane = threadIdx.x & 63;
    int v = blockIdx.x * 4 + wave;
    if (v >= N) return;
    float dv = dinv[v];
    float acc = bias[lane] + dv * dv * h[(size_t)v * 64 + lane];
    int e0 = rowptr[v], e1 = rowptr[v + 1];
    int e = e0;
    for (; e + 4 <= e1; e += 4) {
        int u0 = adj[e], u1 = adj[e + 1], u2 = adj[e + 2], u3 = adj[e + 3];
        float c0f = coef[e], c1f = coef[e + 1], c2f = coef[e + 2], c3f = coef[e + 3];
        float h0 = h[(size_t)u0 * 64 + lane];
        float h1 = h[(size_t)u1 * 64 + lane];
        float h2 = h[(size_t)u2 * 64 + lane];
        float h3 = h[(size_t)u3 * 64 + lane];
        acc += c0f * h0 + c1f * h1 + c2f * h2 + c3f * h3;
    }
    for (; e < e1; e++) {
        acc += coef[e] * h[(size_t)adj[e] * 64 + lane];
    }
    out[(size_t)v * 64 + lane] = acc;
}

extern "C" void kernel_launch(void* const* d_in, const int* in_sizes, int n_in,
                              void* d_out, int out_size, void* d_ws, size_t ws_size,
                              hipStream_t stream) {
    const float* x    = (const float*)d_in[0];
    const void*  eidx = d_in[1];
    const float* W0 = (const float*)d_in[2];
    const float* b0 = (const float*)d_in[3];
    const float* W1 = (const float*)d_in[4];
    const float* b1 = (const float*)d_in[5];
    const float* W2 = (const float*)d_in[6];
    const float* b2 = (const float*)d_in[7];
    const float* g0 = (const float*)d_in[8];
    const float* bn0 = (const float*)d_in[9];
    const float* g1 = (const float*)d_in[10];
    const float* bn1 = (const float*)d_in[11];

    int N = in_sizes[0] / 128;
    int E = in_sizes[1] / 2;

    char* p = (char*)d_ws;
    auto alloc = [&](size_t bytes) {
        char* r = p;
        p += (bytes + 255) & ~(size_t)255;
        return r;
    };
    int*   flag   = (int*)alloc(4);
    int*   src32  = (int*)alloc((size_t)E * 4);
    int*   dst32  = (int*)alloc((size_t)E * 4);
    int*   cnt    = (int*)alloc((size_t)N * 4);
    int*   rowptr = (int*)alloc(((size_t)N + 1) * 4);
    int*   cursor = (int*)alloc((size_t)N * 4);
    float* dinv   = (float*)alloc((size_t)N * 4);
    int*   adj    = (int*)alloc((size_t)E * 4);
    float* coef   = (float*)alloc((size_t)E * 4);
    int*   bsums  = (int*)alloc(4096);
    __bf16* wt0   = (__bf16*)alloc(2 * 128 * KPAD * 2);
    __bf16* wt1   = (__bf16*)alloc(2 * 128 * KPAD * 2);
    __bf16* wt2   = (__bf16*)alloc(2 * 64 * KPAD * 2);
    float* bufA   = (float*)alloc((size_t)N * 128 * 4);
    float* bufB   = (float*)alloc((size_t)N * 128 * 4);

    int eb = (E + 255) / 256;
    int nb = (N + 255) / 256;
    int nscan = (N + SCAN_CHUNK - 1) / SCAN_CHUNK;

    k_detect<<<1, 64, 0, stream>>>((const uint32_t*)eidx, flag);
    hipMemsetAsync(cnt, 0, (size_t)N * 4, stream);
    k_wconv<<<dim3(64, 3), 256, 0, stream>>>(W0, W1, W2, wt0, wt1, wt2);
    k_convert_count<<<eb, 256, 0, stream>>>(eidx, flag, src32, dst32, cnt, E);
    k_scan1<<<nscan, 256, 0, stream>>>(cnt, rowptr, bsums, N);
    k_scan2<<<1, 64, 0, stream>>>(bsums, nscan);
    k_scan3_prep<<<nb, 256, 0, stream>>>(rowptr, bsums, cnt, cursor, dinv, N, E);
    k_fill<<<eb, 256, 0, stream>>>(src32, dst32, cursor, adj, coef, dinv, E);

    int gemmb = (N + 127) / 128;
    int aggb = (N + 3) / 4;

    k_gemm_mfma<128><<<gemmb, 256, 0, stream>>>(x, wt0, bufA, N);
    k_agg_ln<<<aggb, 256, 0, stream>>>(bufA, rowptr, adj, coef, dinv, b0, g0, bn0, bufB, N);
    k_gemm_mfma<128><<<gemmb, 256, 0, stream>>>(bufB, wt1, bufA, N);
    k_agg_ln<<<aggb, 256, 0, stream>>>(bufA, rowptr, adj, coef, dinv, b1, g1, bn1, bufB, N);
    k_gemm_mfma<64><<<gemmb, 256, 0, stream>>>(bufB, wt2, bufA, N);
    k_agg_out<<<aggb, 256, 0, stream>>>(bufA, rowptr, adj, coef, dinv, b2, (float*)d_out, N);
}

// Round 4
// 362.884 us; speedup vs baseline: 3.0934x; 1.1570x over previous
//
#include <hip/hip_runtime.h>
#include <hip/hip_bf16.h>
#include <stdint.h>

#define EPS 1e-5f
#define KPAD 136   // 128 k + 8 pad (bf16) -> 272B row stride

typedef __attribute__((ext_vector_type(8))) __bf16 bf16x8;
typedef __attribute__((ext_vector_type(4))) float f32x4;
typedef _Float16 f16;
typedef __attribute__((ext_vector_type(2))) _Float16 f16x2;
typedef __attribute__((ext_vector_type(8))) _Float16 f16x8;

// ---------------- edge dtype detection (1 wave, parallel) ----------------
__global__ void k_detect(const uint32_t* __restrict__ e, int* __restrict__ flag) {
    int lane = threadIdx.x;
    uint32_t w = e[1 + 2 * lane] | e[129 + 2 * lane];   // odd words 1..255
    int any = __any(w != 0u);
    if (lane == 0) *flag = !any;   // all odd words zero -> int64
}

// ---------------- convert + degree count (fused) ----------------
__global__ void k_convert_count(const void* __restrict__ eidx, const int* __restrict__ flag,
                                int* __restrict__ src, int* __restrict__ dst,
                                int* __restrict__ cnt, int E) {
    int e = blockIdx.x * blockDim.x + threadIdx.x;
    if (e >= E) return;
    int s, d;
    if (*flag) {
        const long long* p = (const long long*)eidx;
        s = (int)p[e];
        d = (int)p[(size_t)E + e];
    } else {
        const int* p = (const int*)eidx;
        s = p[e];
        d = p[(size_t)E + e];
    }
    src[e] = s;
    dst[e] = d;
    atomicAdd(&cnt[d], 1);
}

// ---------------- exclusive scan ----------------
#define SCAN_CHUNK 2048
__global__ void k_scan1(const int* __restrict__ cnt, int* __restrict__ outp,
                        int* __restrict__ bsums, int N) {
    __shared__ int sm[256];
    int t = threadIdx.x;
    int base = blockIdx.x * SCAN_CHUNK + t * 8;
    int v[8];
    int s = 0;
    #pragma unroll
    for (int i = 0; i < 8; i++) {
        int idx = base + i;
        int x = (idx < N) ? cnt[idx] : 0;
        v[i] = s;
        s += x;
    }
    sm[t] = s;
    __syncthreads();
    for (int off = 1; off < 256; off <<= 1) {
        int tv = (t >= off) ? sm[t - off] : 0;
        __syncthreads();
        sm[t] += tv;
        __syncthreads();
    }
    int texcl = (t == 0) ? 0 : sm[t - 1];
    #pragma unroll
    for (int i = 0; i < 8; i++) {
        int idx = base + i;
        if (idx < N) outp[idx] = v[i] + texcl;
    }
    if (t == 255) bsums[blockIdx.x] = sm[255];
}

// single-wave shuffle scan with carry (nb arbitrary)
__global__ void k_scan2(int* __restrict__ bsums, int nb) {
    int lane = threadIdx.x;
    int carry = 0;
    for (int base = 0; base < nb; base += 64) {
        int i = base + lane;
        int v = (i < nb) ? bsums[i] : 0;
        int orig = v;
        #pragma unroll
        for (int off = 1; off < 64; off <<= 1) {
            int t = __shfl_up(v, off);
            if (lane >= off) v += t;
        }
        if (i < nb) bsums[i] = carry + v - orig;
        carry += __shfl(v, 63);
    }
}

__global__ void k_scan3_prep(int* __restrict__ rowptr, const int* __restrict__ bsums,
                             const int* __restrict__ cnt, int* __restrict__ cursor,
                             float* __restrict__ dinv, int N, int E) {
    int i = blockIdx.x * blockDim.x + threadIdx.x;
    if (i < N) {
        int rp = rowptr[i] + bsums[i / SCAN_CHUNK];
        rowptr[i] = rp;
        cursor[i] = rp;
        dinv[i] = rsqrtf((float)(cnt[i] + 1));
    }
    if (i == 0) rowptr[N] = E;
}

__global__ void k_fill(const int* __restrict__ src, const int* __restrict__ dst,
                       int* __restrict__ cursor, int* __restrict__ adj,
                       float* __restrict__ coef, const float* __restrict__ dinv, int E) {
    int e = blockIdx.x * blockDim.x + threadIdx.x;
    if (e < E) {
        int s = src[e], d = dst[e];
        int pos = atomicAdd(&cursor[d], 1);
        adj[pos] = s;
        coef[pos] = dinv[s] * dinv[d];
    }
}

// ---------------- W -> transposed padded bf16 hi/lo ----------------
__global__ void k_wconv(const float* __restrict__ W0, const float* __restrict__ W1,
                        const float* __restrict__ W2, __bf16* __restrict__ T0,
                        __bf16* __restrict__ T1, __bf16* __restrict__ T2) {
    int layer = blockIdx.y;
    const float* W = layer == 0 ? W0 : (layer == 1 ? W1 : W2);
    __bf16* T = layer == 0 ? T0 : (layer == 1 ? T1 : T2);
    int outc = (layer == 2) ? 64 : 128;
    int tid = blockIdx.x * 256 + threadIdx.x;
    if (tid >= 128 * outc) return;
    int k = tid / outc, c = tid % outc;
    float f = W[tid];
    __bf16 hb = (__bf16)f;
    __bf16 lb = (__bf16)(f - (float)hb);
    T[c * KPAD + k] = hb;
    T[outc * KPAD + c * KPAD + k] = lb;
}

// ---------------- MFMA GEMM: C[N x OUTC](f16) = A[N x 128] @ W[128 x OUTC] ----------------
// bf16 hi/lo 3-MFMA split (~fp32 accuracy). Block = 4 waves x 32 rows = 128 rows.
template <int OUTC, typename AT>
__global__ __launch_bounds__(256, 2) void k_gemm_mfma(const AT* __restrict__ A,
                                                      const __bf16* __restrict__ WT,
                                                      f16* __restrict__ C, int N) {
    __shared__ __bf16 lds[2 * OUTC * KPAD];
    const int t = threadIdx.x;
    const int n16 = (2 * OUTC * KPAD * 2) / 16;
    for (int i = t; i < n16; i += 256)
        ((float4*)lds)[i] = ((const float4*)WT)[i];

    const int lane = t & 63;
    const int wv = t >> 6;
    const int c = lane & 15;
    const int hq = lane >> 4;
    const int rowbase = blockIdx.x * 128 + wv * 32;

    // A fragment: row = lane&15, k = ks*32 + 8*hq + j
    bf16x8 ahi[2][4], alo[2][4];
    #pragma unroll
    for (int rt = 0; rt < 2; ++rt) {
        int ar = rowbase + rt * 16 + c;
        if (ar > N - 1) ar = N - 1;
        const AT* ap = A + (size_t)ar * 128 + hq * 8;
        #pragma unroll
        for (int ks = 0; ks < 4; ++ks) {
            float v[8];
            if constexpr (sizeof(AT) == 4) {
                float4 p = *(const float4*)(ap + ks * 32);
                float4 q = *(const float4*)(ap + ks * 32 + 4);
                v[0] = p.x; v[1] = p.y; v[2] = p.z; v[3] = p.w;
                v[4] = q.x; v[5] = q.y; v[6] = q.z; v[7] = q.w;
            } else {
                f16x8 r = *(const f16x8*)(ap + ks * 32);
                #pragma unroll
                for (int j = 0; j < 8; ++j) v[j] = (float)r[j];
            }
            #pragma unroll
            for (int j = 0; j < 8; ++j) {
                __bf16 hb = (__bf16)v[j];
                ahi[rt][ks][j] = hb;
                alo[rt][ks][j] = (__bf16)(v[j] - (float)hb);
            }
        }
    }
    __syncthreads();

    #pragma unroll
    for (int ct = 0; ct < OUTC / 16; ++ct) {
        const __bf16* bp = &lds[(ct * 16 + c) * KPAD + hq * 8];
        bf16x8 bhi[4], blo[4];
        #pragma unroll
        for (int ks = 0; ks < 4; ++ks) {
            bhi[ks] = *reinterpret_cast<const bf16x8*>(bp + ks * 32);
            blo[ks] = *reinterpret_cast<const bf16x8*>(bp + OUTC * KPAD + ks * 32);
        }
        f32x4 acc0 = {0.f, 0.f, 0.f, 0.f};
        f32x4 acc1 = {0.f, 0.f, 0.f, 0.f};
        #pragma unroll
        for (int ks = 0; ks < 4; ++ks) {
            acc0 = __builtin_amdgcn_mfma_f32_16x16x32_bf16(ahi[0][ks], bhi[ks], acc0, 0, 0, 0);
            acc1 = __builtin_amdgcn_mfma_f32_16x16x32_bf16(ahi[1][ks], bhi[ks], acc1, 0, 0, 0);
            acc0 = __builtin_amdgcn_mfma_f32_16x16x32_bf16(alo[0][ks], bhi[ks], acc0, 0, 0, 0);
            acc1 = __builtin_amdgcn_mfma_f32_16x16x32_bf16(alo[1][ks], bhi[ks], acc1, 0, 0, 0);
            acc0 = __builtin_amdgcn_mfma_f32_16x16x32_bf16(ahi[0][ks], blo[ks], acc0, 0, 0, 0);
            acc1 = __builtin_amdgcn_mfma_f32_16x16x32_bf16(ahi[1][ks], blo[ks], acc1, 0, 0, 0);
        }
        const int col = ct * 16 + c;
        #pragma unroll
        for (int rt = 0; rt < 2; ++rt) {
            f32x4 a = rt ? acc1 : acc0;
            int row0 = rowbase + rt * 16 + hq * 4;
            #pragma unroll
            for (int r = 0; r < 4; ++r) {
                int row = row0 + r;
                if (row < N) C[(size_t)row * OUTC + col] = (f16)a[r];
            }
        }
    }
}

// ---------------- aggregation + LayerNorm + ReLU (128 cols f16, 1 wave/node) ----------------
__global__ __launch_bounds__(256) void k_agg_ln(const f16* __restrict__ h,
                                                const int* __restrict__ rowptr,
                                                const int* __restrict__ adj,
                                                const float* __restrict__ coef,
                                                const float* __restrict__ dinv,
                                                const float* __restrict__ bias,
                                                const float* __restrict__ g,
                                                const float* __restrict__ bn,
                                                f16* __restrict__ out, int N) {
    int wave = threadIdx.x >> 6;
    int lane = threadIdx.x & 63;
    int v = blockIdx.x * 4 + wave;
    if (v >= N) return;
    int c = lane * 2;
    float dv = dinv[v];
    f16x2 hv = *(const f16x2*)&h[(size_t)v * 128 + c];
    float2 bb = *(const float2*)&bias[c];
    float cs = dv * dv;
    float ax = bb.x + cs * (float)hv[0];
    float ay = bb.y + cs * (float)hv[1];
    int e0 = rowptr[v], e1 = rowptr[v + 1];
    int e = e0;
    for (; e + 8 <= e1; e += 8) {
        int u[8];
        float cf[8];
        f16x2 hh[8];
        #pragma unroll
        for (int i = 0; i < 8; i++) { u[i] = adj[e + i]; cf[i] = coef[e + i]; }
        #pragma unroll
        for (int i = 0; i < 8; i++) hh[i] = *(const f16x2*)&h[(size_t)u[i] * 128 + c];
        #pragma unroll
        for (int i = 0; i < 8; i++) {
            ax += cf[i] * (float)hh[i][0];
            ay += cf[i] * (float)hh[i][1];
        }
    }
    for (; e < e1; e++) {
        int u = adj[e];
        float cf = coef[e];
        f16x2 hu = *(const f16x2*)&h[(size_t)u * 128 + c];
        ax += cf * (float)hu[0];
        ay += cf * (float)hu[1];
    }
    float s = ax + ay;
    #pragma unroll
    for (int m = 32; m >= 1; m >>= 1) s += __shfl_xor(s, m);
    float mu = s * (1.0f / 128.0f);
    float dx = ax - mu, dy = ay - mu;
    float vs = dx * dx + dy * dy;
    #pragma unroll
    for (int m = 32; m >= 1; m >>= 1) vs += __shfl_xor(vs, m);
    float rs = rsqrtf(vs * (1.0f / 128.0f) + EPS);
    float2 gg = *(const float2*)&g[c];
    float2 bnv = *(const float2*)&bn[c];
    float ox = fmaxf(dx * rs * gg.x + bnv.x, 0.0f);
    float oy = fmaxf(dy * rs * gg.y + bnv.y, 0.0f);
    f16x2 o;
    o[0] = (f16)ox;
    o[1] = (f16)oy;
    *(f16x2*)&out[(size_t)v * 128 + c] = o;
}

// ---------------- aggregation + bias (64 cols f16 in, f32 out; half-wave split) ----------------
__global__ __launch_bounds__(256) void k_agg_out(const f16* __restrict__ h,
                                                 const int* __restrict__ rowptr,
                                                 const int* __restrict__ adj,
                                                 const float* __restrict__ coef,
                                                 const float* __restrict__ dinv,
                                                 const float* __restrict__ bias,
                                                 float* __restrict__ out, int N) {
    int wave = threadIdx.x >> 6;
    int lane = threadIdx.x & 63;
    int v = blockIdx.x * 4 + wave;
    if (v >= N) return;
    int half = lane >> 5;
    int c = (lane & 31) * 2;
    float dv = dinv[v];
    float ax = 0.f, ay = 0.f;
    if (half == 0) {
        f16x2 hv = *(const f16x2*)&h[(size_t)v * 64 + c];
        float2 bb = *(const float2*)&bias[c];
        float cs = dv * dv;
        ax = bb.x + cs * (float)hv[0];
        ay = bb.y + cs * (float)hv[1];
    }
    int e0 = rowptr[v], e1 = rowptr[v + 1];
    int e = e0 + half;
    for (; e + 6 < e1; e += 8) {
        int u0 = adj[e], u1 = adj[e + 2], u2 = adj[e + 4], u3 = adj[e + 6];
        float c0 = coef[e], c1 = coef[e + 2], c2 = coef[e + 4], c3 = coef[e + 6];
        f16x2 h0 = *(const f16x2*)&h[(size_t)u0 * 64 + c];
        f16x2 h1 = *(const f16x2*)&h[(size_t)u1 * 64 + c];
        f16x2 h2 = *(const f16x2*)&h[(size_t)u2 * 64 + c];
        f16x2 h3 = *(const f16x2*)&h[(size_t)u3 * 64 + c];
        ax += c0 * (float)h0[0] + c1 * (float)h1[0] + c2 * (float)h2[0] + c3 * (float)h3[0];
        ay += c0 * (float)h0[1] + c1 * (float)h1[1] + c2 * (float)h2[1] + c3 * (float)h3[1];
    }
    for (; e < e1; e += 2) {
        int u = adj[e];
        float cf = coef[e];
        f16x2 hu = *(const f16x2*)&h[(size_t)u * 64 + c];
        ax += cf * (float)hu[0];
        ay += cf * (float)hu[1];
    }
    ax += __shfl_xor(ax, 32);
    ay += __shfl_xor(ay, 32);
    if (half == 0) *(float2*)&out[(size_t)v * 64 + c] = make_float2(ax, ay);
}

extern "C" void kernel_launch(void* const* d_in, const int* in_sizes, int n_in,
                              void* d_out, int out_size, void* d_ws, size_t ws_size,
                              hipStream_t stream) {
    const float* x    = (const float*)d_in[0];
    const void*  eidx = d_in[1];
    const float* W0 = (const float*)d_in[2];
    const float* b0 = (const float*)d_in[3];
    const float* W1 = (const float*)d_in[4];
    const float* b1 = (const float*)d_in[5];
    const float* W2 = (const float*)d_in[6];
    const float* b2 = (const float*)d_in[7];
    const float* g0 = (const float*)d_in[8];
    const float* bn0 = (const float*)d_in[9];
    const float* g1 = (const float*)d_in[10];
    const float* bn1 = (const float*)d_in[11];

    int N = in_sizes[0] / 128;
    int E = in_sizes[1] / 2;

    char* p = (char*)d_ws;
    auto alloc = [&](size_t bytes) {
        char* r = p;
        p += (bytes + 255) & ~(size_t)255;
        return r;
    };
    int*   flag   = (int*)alloc(4);
    int*   src32  = (int*)alloc((size_t)E * 4);
    int*   dst32  = (int*)alloc((size_t)E * 4);
    int*   cnt    = (int*)alloc((size_t)N * 4);
    int*   rowptr = (int*)alloc(((size_t)N + 1) * 4);
    int*   cursor = (int*)alloc((size_t)N * 4);
    float* dinv   = (float*)alloc((size_t)N * 4);
    int*   adj    = (int*)alloc((size_t)E * 4);
    float* coef   = (float*)alloc((size_t)E * 4);
    int*   bsums  = (int*)alloc(4096);
    __bf16* wt0   = (__bf16*)alloc(2 * 128 * KPAD * 2);
    __bf16* wt1   = (__bf16*)alloc(2 * 128 * KPAD * 2);
    __bf16* wt2   = (__bf16*)alloc(2 * 64 * KPAD * 2);
    f16*   bufA   = (f16*)alloc((size_t)N * 128 * 2);
    f16*   bufB   = (f16*)alloc((size_t)N * 128 * 2);

    int eb = (E + 255) / 256;
    int nb = (N + 255) / 256;
    int nscan = (N + SCAN_CHUNK - 1) / SCAN_CHUNK;

    k_detect<<<1, 64, 0, stream>>>((const uint32_t*)eidx, flag);
    hipMemsetAsync(cnt, 0, (size_t)N * 4, stream);
    k_wconv<<<dim3(64, 3), 256, 0, stream>>>(W0, W1, W2, wt0, wt1, wt2);
    k_convert_count<<<eb, 256, 0, stream>>>(eidx, flag, src32, dst32, cnt, E);
    k_scan1<<<nscan, 256, 0, stream>>>(cnt, rowptr, bsums, N);
    k_scan2<<<1, 64, 0, stream>>>(bsums, nscan);
    k_scan3_prep<<<nb, 256, 0, stream>>>(rowptr, bsums, cnt, cursor, dinv, N, E);
    k_fill<<<eb, 256, 0, stream>>>(src32, dst32, cursor, adj, coef, dinv, E);

    int gemmb = (N + 127) / 128;
    int aggb = (N + 3) / 4;

    k_gemm_mfma<128, float><<<gemmb, 256, 0, stream>>>(x, wt0, bufA, N);
    k_agg_ln<<<aggb, 256, 0, stream>>>(bufA, rowptr, adj, coef, dinv, b0, g0, bn0, bufB, N);
    k_gemm_mfma<128, f16><<<gemmb, 256, 0, stream>>>(bufB, wt1, bufA, N);
    k_agg_ln<<<aggb, 256, 0, stream>>>(bufA, rowptr, adj, coef, dinv, b1, g1, bn1, bufB, N);
    k_gemm_mfma<64, f16><<<gemmb, 256, 0, stream>>>(bufB, wt2, bufA, N);
    k_agg_out<<<aggb, 256, 0, stream>>>(bufA, rowptr, adj, coef, dinv, b2, (float*)d_out, N);
}

// Round 5
// 339.361 us; speedup vs baseline: 3.3079x; 1.0693x over previous
//
#include <hip/hip_runtime.h>
#include <hip/hip_bf16.h>
#include <stdint.h>

#define EPS 1e-5f
#define KPAD 136   // 128 k + 8 pad (bf16) -> 272B row stride

typedef __attribute__((ext_vector_type(8))) __bf16 bf16x8;
typedef __attribute__((ext_vector_type(4))) float f32x4;
typedef _Float16 f16;
typedef __attribute__((ext_vector_type(2))) _Float16 f16x2;
typedef __attribute__((ext_vector_type(8))) _Float16 f16x8;

__device__ __forceinline__ int rfl(int x) { return __builtin_amdgcn_readfirstlane(x); }
__device__ __forceinline__ float rflf(float x) {
    return __int_as_float(__builtin_amdgcn_readfirstlane(__float_as_int(x)));
}

// ---------------- edge dtype detection (1 wave, parallel) ----------------
__global__ void k_detect(const uint32_t* __restrict__ e, int* __restrict__ flag) {
    int lane = threadIdx.x;
    uint32_t w = e[1 + 2 * lane] | e[129 + 2 * lane];
    int any = __any(w != 0u);
    if (lane == 0) *flag = !any;
}

// ---------------- convert + degree count (fused) ----------------
__global__ void k_convert_count(const void* __restrict__ eidx, const int* __restrict__ flag,
                                int* __restrict__ src, int* __restrict__ dst,
                                int* __restrict__ cnt, int E) {
    int e = blockIdx.x * blockDim.x + threadIdx.x;
    if (e >= E) return;
    int s, d;
    if (*flag) {
        const long long* p = (const long long*)eidx;
        s = (int)p[e];
        d = (int)p[(size_t)E + e];
    } else {
        const int* p = (const int*)eidx;
        s = p[e];
        d = p[(size_t)E + e];
    }
    src[e] = s;
    dst[e] = d;
    atomicAdd(&cnt[d], 1);
}

// ---------------- exclusive scan ----------------
#define SCAN_CHUNK 2048
__global__ void k_scan1(const int* __restrict__ cnt, int* __restrict__ outp,
                        int* __restrict__ bsums, int N) {
    __shared__ int sm[256];
    int t = threadIdx.x;
    int base = blockIdx.x * SCAN_CHUNK + t * 8;
    int v[8];
    int s = 0;
    #pragma unroll
    for (int i = 0; i < 8; i++) {
        int idx = base + i;
        int x = (idx < N) ? cnt[idx] : 0;
        v[i] = s;
        s += x;
    }
    sm[t] = s;
    __syncthreads();
    for (int off = 1; off < 256; off <<= 1) {
        int tv = (t >= off) ? sm[t - off] : 0;
        __syncthreads();
        sm[t] += tv;
        __syncthreads();
    }
    int texcl = (t == 0) ? 0 : sm[t - 1];
    #pragma unroll
    for (int i = 0; i < 8; i++) {
        int idx = base + i;
        if (idx < N) outp[idx] = v[i] + texcl;
    }
    if (t == 255) bsums[blockIdx.x] = sm[255];
}

__global__ void k_scan2(int* __restrict__ bsums, int nb) {
    int lane = threadIdx.x;
    int carry = 0;
    for (int base = 0; base < nb; base += 64) {
        int i = base + lane;
        int v = (i < nb) ? bsums[i] : 0;
        int orig = v;
        #pragma unroll
        for (int off = 1; off < 64; off <<= 1) {
            int t = __shfl_up(v, off);
            if (lane >= off) v += t;
        }
        if (i < nb) bsums[i] = carry + v - orig;
        carry += __shfl(v, 63);
    }
}

__global__ void k_scan3_prep(int* __restrict__ rowptr, const int* __restrict__ bsums,
                             const int* __restrict__ cnt, int* __restrict__ cursor,
                             float* __restrict__ dinv, int N, int E) {
    int i = blockIdx.x * blockDim.x + threadIdx.x;
    if (i < N) {
        int rp = rowptr[i] + bsums[i / SCAN_CHUNK];
        rowptr[i] = rp;
        cursor[i] = rp;
        dinv[i] = rsqrtf((float)(cnt[i] + 1));
    }
    if (i == 0) rowptr[N] = E;
}

__global__ void k_fill(const int* __restrict__ src, const int* __restrict__ dst,
                       int* __restrict__ cursor, int* __restrict__ adj,
                       float* __restrict__ coef, const float* __restrict__ dinv, int E) {
    int e = blockIdx.x * blockDim.x + threadIdx.x;
    if (e < E) {
        int s = src[e], d = dst[e];
        int pos = atomicAdd(&cursor[d], 1);
        adj[pos] = s;
        coef[pos] = dinv[s] * dinv[d];
    }
}

// ---------------- W -> transposed padded bf16 hi/lo ----------------
__global__ void k_wconv(const float* __restrict__ W0, const float* __restrict__ W1,
                        const float* __restrict__ W2, __bf16* __restrict__ T0,
                        __bf16* __restrict__ T1, __bf16* __restrict__ T2) {
    int layer = blockIdx.y;
    const float* W = layer == 0 ? W0 : (layer == 1 ? W1 : W2);
    __bf16* T = layer == 0 ? T0 : (layer == 1 ? T1 : T2);
    int outc = (layer == 2) ? 64 : 128;
    int tid = blockIdx.x * 256 + threadIdx.x;
    if (tid >= 128 * outc) return;
    int k = tid / outc, c = tid % outc;
    float f = W[tid];
    __bf16 hb = (__bf16)f;
    __bf16 lb = (__bf16)(f - (float)hb);
    T[c * KPAD + k] = hb;
    T[outc * KPAD + c * KPAD + k] = lb;
}

// ---------------- MFMA GEMM: C[N x OUTC](f16) = A[N x 128] @ W[128 x OUTC] ----------------
template <int OUTC, typename AT>
__global__ __launch_bounds__(256, 2) void k_gemm_mfma(const AT* __restrict__ A,
                                                      const __bf16* __restrict__ WT,
                                                      f16* __restrict__ C, int N) {
    __shared__ __bf16 lds[2 * OUTC * KPAD];
    const int t = threadIdx.x;
    const int n16 = (2 * OUTC * KPAD * 2) / 16;
    for (int i = t; i < n16; i += 256)
        ((float4*)lds)[i] = ((const float4*)WT)[i];

    const int lane = t & 63;
    const int wv = t >> 6;
    const int c = lane & 15;
    const int hq = lane >> 4;
    const int rowbase = blockIdx.x * 128 + wv * 32;

    bf16x8 ahi[2][4], alo[2][4];
    #pragma unroll
    for (int rt = 0; rt < 2; ++rt) {
        int ar = rowbase + rt * 16 + c;
        if (ar > N - 1) ar = N - 1;
        const AT* ap = A + (size_t)ar * 128 + hq * 8;
        #pragma unroll
        for (int ks = 0; ks < 4; ++ks) {
            float v[8];
            if constexpr (sizeof(AT) == 4) {
                float4 p = *(const float4*)(ap + ks * 32);
                float4 q = *(const float4*)(ap + ks * 32 + 4);
                v[0] = p.x; v[1] = p.y; v[2] = p.z; v[3] = p.w;
                v[4] = q.x; v[5] = q.y; v[6] = q.z; v[7] = q.w;
            } else {
                f16x8 r = *(const f16x8*)(ap + ks * 32);
                #pragma unroll
                for (int j = 0; j < 8; ++j) v[j] = (float)r[j];
            }
            #pragma unroll
            for (int j = 0; j < 8; ++j) {
                __bf16 hb = (__bf16)v[j];
                ahi[rt][ks][j] = hb;
                alo[rt][ks][j] = (__bf16)(v[j] - (float)hb);
            }
        }
    }
    __syncthreads();

    #pragma unroll
    for (int ct = 0; ct < OUTC / 16; ++ct) {
        const __bf16* bp = &lds[(ct * 16 + c) * KPAD + hq * 8];
        bf16x8 bhi[4], blo[4];
        #pragma unroll
        for (int ks = 0; ks < 4; ++ks) {
            bhi[ks] = *reinterpret_cast<const bf16x8*>(bp + ks * 32);
            blo[ks] = *reinterpret_cast<const bf16x8*>(bp + OUTC * KPAD + ks * 32);
        }
        f32x4 acc0 = {0.f, 0.f, 0.f, 0.f};
        f32x4 acc1 = {0.f, 0.f, 0.f, 0.f};
        #pragma unroll
        for (int ks = 0; ks < 4; ++ks) {
            acc0 = __builtin_amdgcn_mfma_f32_16x16x32_bf16(ahi[0][ks], bhi[ks], acc0, 0, 0, 0);
            acc1 = __builtin_amdgcn_mfma_f32_16x16x32_bf16(ahi[1][ks], bhi[ks], acc1, 0, 0, 0);
            acc0 = __builtin_amdgcn_mfma_f32_16x16x32_bf16(alo[0][ks], bhi[ks], acc0, 0, 0, 0);
            acc1 = __builtin_amdgcn_mfma_f32_16x16x32_bf16(alo[1][ks], bhi[ks], acc1, 0, 0, 0);
            acc0 = __builtin_amdgcn_mfma_f32_16x16x32_bf16(ahi[0][ks], blo[ks], acc0, 0, 0, 0);
            acc1 = __builtin_amdgcn_mfma_f32_16x16x32_bf16(ahi[1][ks], blo[ks], acc1, 0, 0, 0);
        }
        const int col = ct * 16 + c;
        #pragma unroll
        for (int rt = 0; rt < 2; ++rt) {
            f32x4 a = rt ? acc1 : acc0;
            int row0 = rowbase + rt * 16 + hq * 4;
            #pragma unroll
            for (int r = 0; r < 4; ++r) {
                int row = row0 + r;
                if (row < N) C[(size_t)row * OUTC + col] = (f16)a[r];
            }
        }
    }
}

// ---------------- aggregation + LayerNorm + ReLU (128 cols f16, 1 wave/node) ----------------
// All wave-uniform values (node id, edge range, neighbor ids, coefs) forced to SGPRs.
__global__ __launch_bounds__(256) void k_agg_ln(const f16* __restrict__ h,
                                                const int* __restrict__ rowptr,
                                                const int* __restrict__ adj,
                                                const float* __restrict__ coef,
                                                const float* __restrict__ dinv,
                                                const float* __restrict__ bias,
                                                const float* __restrict__ g,
                                                const float* __restrict__ bn,
                                                f16* __restrict__ out, int N) {
    int lane = threadIdx.x & 63;
    int v = rfl(blockIdx.x * 4 + (threadIdx.x >> 6));
    if (v >= N) return;
    int c = lane * 2;
    float dv = rflf(dinv[v]);
    float cs = dv * dv;
    f16x2 hv = *(const f16x2*)&h[(size_t)v * 128 + c];
    float2 bb = *(const float2*)&bias[c];
    float ax = fmaf(cs, (float)hv[0], bb.x);
    float ay = fmaf(cs, (float)hv[1], bb.y);
    int e0 = rfl(rowptr[v]);
    int e1 = rfl(rowptr[v + 1]);
    int e = e0;
    for (; e + 8 <= e1; e += 8) {
        const f16* rp[8];
        float cf[8];
        #pragma unroll
        for (int i = 0; i < 8; i++) {
            int u = rfl(adj[e + i]);
            cf[i] = rflf(coef[e + i]);
            rp[i] = h + (size_t)u * 128;
        }
        f16x2 hh[8];
        #pragma unroll
        for (int i = 0; i < 8; i++) hh[i] = *(const f16x2*)&rp[i][c];
        #pragma unroll
        for (int i = 0; i < 8; i++) {
            ax += cf[i] * (float)hh[i][0];
            ay += cf[i] * (float)hh[i][1];
        }
    }
    for (; e < e1; e++) {
        int u = rfl(adj[e]);
        float cf = rflf(coef[e]);
        f16x2 hu = *(const f16x2*)&h[(size_t)u * 128 + c];
        ax += cf * (float)hu[0];
        ay += cf * (float)hu[1];
    }
    float s = ax + ay;
    #pragma unroll
    for (int m = 32; m >= 1; m >>= 1) s += __shfl_xor(s, m);
    float mu = s * (1.0f / 128.0f);
    float dx = ax - mu, dy = ay - mu;
    float vs = dx * dx + dy * dy;
    #pragma unroll
    for (int m = 32; m >= 1; m >>= 1) vs += __shfl_xor(vs, m);
    float rs = rsqrtf(vs * (1.0f / 128.0f) + EPS);
    float2 gg = *(const float2*)&g[c];
    float2 bnv = *(const float2*)&bn[c];
    float ox = fmaxf(dx * rs * gg.x + bnv.x, 0.0f);
    float oy = fmaxf(dy * rs * gg.y + bnv.y, 0.0f);
    f16x2 o;
    o[0] = (f16)ox;
    o[1] = (f16)oy;
    *(f16x2*)&out[(size_t)v * 128 + c] = o;
}

// ---------------- aggregation + bias (64 cols f16 in, f32 out; 1 col/lane) ----------------
__global__ __launch_bounds__(256) void k_agg_out(const f16* __restrict__ h,
                                                 const int* __restrict__ rowptr,
                                                 const int* __restrict__ adj,
                                                 const float* __restrict__ coef,
                                                 const float* __restrict__ dinv,
                                                 const float* __restrict__ bias,
                                                 float* __restrict__ out, int N) {
    int lane = threadIdx.x & 63;
    int v = rfl(blockIdx.x * 4 + (threadIdx.x >> 6));
    if (v >= N) return;
    float dv = rflf(dinv[v]);
    float cs = dv * dv;
    float acc = fmaf(cs, (float)h[(size_t)v * 64 + lane], bias[lane]);
    int e0 = rfl(rowptr[v]);
    int e1 = rfl(rowptr[v + 1]);
    int e = e0;
    for (; e + 8 <= e1; e += 8) {
        const f16* rp[8];
        float cf[8];
        #pragma unroll
        for (int i = 0; i < 8; i++) {
            int u = rfl(adj[e + i]);
            cf[i] = rflf(coef[e + i]);
            rp[i] = h + (size_t)u * 64;
        }
        f16 hh[8];
        #pragma unroll
        for (int i = 0; i < 8; i++) hh[i] = rp[i][lane];
        #pragma unroll
        for (int i = 0; i < 8; i++) acc += cf[i] * (float)hh[i];
    }
    for (; e < e1; e++) {
        int u = rfl(adj[e]);
        float cf = rflf(coef[e]);
        acc += cf * (float)h[(size_t)u * 64 + lane];
    }
    out[(size_t)v * 64 + lane] = acc;
}

extern "C" void kernel_launch(void* const* d_in, const int* in_sizes, int n_in,
                              void* d_out, int out_size, void* d_ws, size_t ws_size,
                              hipStream_t stream) {
    const float* x    = (const float*)d_in[0];
    const void*  eidx = d_in[1];
    const float* W0 = (const float*)d_in[2];
    const float* b0 = (const float*)d_in[3];
    const float* W1 = (const float*)d_in[4];
    const float* b1 = (const float*)d_in[5];
    const float* W2 = (const float*)d_in[6];
    const float* b2 = (const float*)d_in[7];
    const float* g0 = (const float*)d_in[8];
    const float* bn0 = (const float*)d_in[9];
    const float* g1 = (const float*)d_in[10];
    const float* bn1 = (const float*)d_in[11];

    int N = in_sizes[0] / 128;
    int E = in_sizes[1] / 2;

    char* p = (char*)d_ws;
    auto alloc = [&](size_t bytes) {
        char* r = p;
        p += (bytes + 255) & ~(size_t)255;
        return r;
    };
    int*   flag   = (int*)alloc(4);
    int*   src32  = (int*)alloc((size_t)E * 4);
    int*   dst32  = (int*)alloc((size_t)E * 4);
    int*   cnt    = (int*)alloc((size_t)N * 4);
    int*   rowptr = (int*)alloc(((size_t)N + 1) * 4);
    int*   cursor = (int*)alloc((size_t)N * 4);
    float* dinv   = (float*)alloc((size_t)N * 4);
    int*   adj    = (int*)alloc((size_t)E * 4);
    float* coef   = (float*)alloc((size_t)E * 4);
    int*   bsums  = (int*)alloc(4096);
    __bf16* wt0   = (__bf16*)alloc(2 * 128 * KPAD * 2);
    __bf16* wt1   = (__bf16*)alloc(2 * 128 * KPAD * 2);
    __bf16* wt2   = (__bf16*)alloc(2 * 64 * KPAD * 2);
    f16*   bufA   = (f16*)alloc((size_t)N * 128 * 2);
    f16*   bufB   = (f16*)alloc((size_t)N * 128 * 2);

    int eb = (E + 255) / 256;
    int nb = (N + 255) / 256;
    int nscan = (N + SCAN_CHUNK - 1) / SCAN_CHUNK;

    k_detect<<<1, 64, 0, stream>>>((const uint32_t*)eidx, flag);
    hipMemsetAsync(cnt, 0, (size_t)N * 4, stream);
    k_wconv<<<dim3(64, 3), 256, 0, stream>>>(W0, W1, W2, wt0, wt1, wt2);
    k_convert_count<<<eb, 256, 0, stream>>>(eidx, flag, src32, dst32, cnt, E);
    k_scan1<<<nscan, 256, 0, stream>>>(cnt, rowptr, bsums, N);
    k_scan2<<<1, 64, 0, stream>>>(bsums, nscan);
    k_scan3_prep<<<nb, 256, 0, stream>>>(rowptr, bsums, cnt, cursor, dinv, N, E);
    k_fill<<<eb, 256, 0, stream>>>(src32, dst32, cursor, adj, coef, dinv, E);

    int gemmb = (N + 127) / 128;
    int aggb = (N + 3) / 4;

    k_gemm_mfma<128, float><<<gemmb, 256, 0, stream>>>(x, wt0, bufA, N);
    k_agg_ln<<<aggb, 256, 0, stream>>>(bufA, rowptr, adj, coef, dinv, b0, g0, bn0, bufB, N);
    k_gemm_mfma<128, f16><<<gemmb, 256, 0, stream>>>(bufB, wt1, bufA, N);
    k_agg_ln<<<aggb, 256, 0, stream>>>(bufA, rowptr, adj, coef, dinv, b1, g1, bn1, bufB, N);
    k_gemm_mfma<64, f16><<<gemmb, 256, 0, stream>>>(bufB, wt2, bufA, N);
    k_agg_out<<<aggb, 256, 0, stream>>>(bufA, rowptr, adj, coef, dinv, b2, (float*)d_out, N);
}

// Round 6
// 320.373 us; speedup vs baseline: 3.5039x; 1.0593x over previous
//
#include <hip/hip_runtime.h>
#include <hip/hip_bf16.h>
#include <stdint.h>

#define EPS 1e-5f
#define KPAD 136   // 128 k + 8 pad (bf16) -> 272B row stride, 2-way-free LDS banks

typedef __attribute__((ext_vector_type(8))) __bf16 bf16x8;
typedef __attribute__((ext_vector_type(4))) float f32x4;
typedef _Float16 f16;
typedef __attribute__((ext_vector_type(2))) _Float16 f16x2;
typedef __attribute__((ext_vector_type(8))) _Float16 f16x8;

__device__ __forceinline__ int rfl(int x) { return __builtin_amdgcn_readfirstlane(x); }
__device__ __forceinline__ float rflf(float x) {
    return __int_as_float(__builtin_amdgcn_readfirstlane(__float_as_int(x)));
}

// ---------------- convert + degree count (detection folded in) ----------------
__global__ void k_convert_count(const void* __restrict__ eidx,
                                int* __restrict__ src, int* __restrict__ dst,
                                int* __restrict__ cnt, int E) {
    const uint32_t* w = (const uint32_t*)eidx;
    int lane = threadIdx.x & 63;
    // int64 little-endian with values < 2^31 => all odd 32-bit words zero
    uint32_t odd = w[1 + 2 * lane] | w[129 + 2 * lane];
    bool is64 = !__any(odd != 0u);
    int e = blockIdx.x * blockDim.x + threadIdx.x;
    if (e >= E) return;
    int s, d;
    if (is64) {
        const long long* p = (const long long*)eidx;
        s = (int)p[e];
        d = (int)p[(size_t)E + e];
    } else {
        const int* p = (const int*)eidx;
        s = p[e];
        d = p[(size_t)E + e];
    }
    src[e] = s;
    dst[e] = d;
    atomicAdd(&cnt[d], 1);
}

// ---------------- exclusive scan ----------------
#define SCAN_CHUNK 2048
__global__ void k_scan1(const int* __restrict__ cnt, int* __restrict__ outp,
                        int* __restrict__ bsums, int N) {
    __shared__ int sm[256];
    int t = threadIdx.x;
    int base = blockIdx.x * SCAN_CHUNK + t * 8;
    int v[8];
    int s = 0;
    #pragma unroll
    for (int i = 0; i < 8; i++) {
        int idx = base + i;
        int x = (idx < N) ? cnt[idx] : 0;
        v[i] = s;
        s += x;
    }
    sm[t] = s;
    __syncthreads();
    for (int off = 1; off < 256; off <<= 1) {
        int tv = (t >= off) ? sm[t - off] : 0;
        __syncthreads();
        sm[t] += tv;
        __syncthreads();
    }
    int texcl = (t == 0) ? 0 : sm[t - 1];
    #pragma unroll
    for (int i = 0; i < 8; i++) {
        int idx = base + i;
        if (idx < N) outp[idx] = v[i] + texcl;
    }
    if (t == 255) bsums[blockIdx.x] = sm[255];
}

__global__ void k_scan2(int* __restrict__ bsums, int nb) {
    int lane = threadIdx.x;
    int carry = 0;
    for (int base = 0; base < nb; base += 64) {
        int i = base + lane;
        int v = (i < nb) ? bsums[i] : 0;
        int orig = v;
        #pragma unroll
        for (int off = 1; off < 64; off <<= 1) {
            int t = __shfl_up(v, off);
            if (lane >= off) v += t;
        }
        if (i < nb) bsums[i] = carry + v - orig;
        carry += __shfl(v, 63);
    }
}

__global__ void k_scan3_prep(int* __restrict__ rowptr, const int* __restrict__ bsums,
                             const int* __restrict__ cnt, int* __restrict__ cursor,
                             float* __restrict__ dinv, int N, int E) {
    int i = blockIdx.x * blockDim.x + threadIdx.x;
    if (i < N) {
        int rp = rowptr[i] + bsums[i / SCAN_CHUNK];
        rowptr[i] = rp;
        cursor[i] = rp;
        dinv[i] = rsqrtf((float)(cnt[i] + 1));
    }
    if (i == 0) rowptr[N] = E;
}

// ---------------- CSR fill (adj only; coef folded into GEMM epilogue) ----------------
__global__ void k_fill(const int* __restrict__ src, const int* __restrict__ dst,
                       int* __restrict__ cursor, int* __restrict__ adj, int E) {
    int e = blockIdx.x * blockDim.x + threadIdx.x;
    if (e < E) {
        int pos = atomicAdd(&cursor[dst[e]], 1);
        adj[pos] = src[e];
    }
}

// ---------------- W -> transposed padded bf16 hi/lo ----------------
__global__ void k_wconv(const float* __restrict__ W0, const float* __restrict__ W1,
                        const float* __restrict__ W2, __bf16* __restrict__ T0,
                        __bf16* __restrict__ T1, __bf16* __restrict__ T2) {
    int layer = blockIdx.y;
    const float* W = layer == 0 ? W0 : (layer == 1 ? W1 : W2);
    __bf16* T = layer == 0 ? T0 : (layer == 1 ? T1 : T2);
    int outc = (layer == 2) ? 64 : 128;
    int tid = blockIdx.x * 256 + threadIdx.x;
    if (tid >= 128 * outc) return;
    int k = tid / outc, c = tid % outc;
    float f = W[tid];
    __bf16 hb = (__bf16)f;
    __bf16 lb = (__bf16)(f - (float)hb);
    T[c * KPAD + k] = hb;
    T[outc * KPAD + c * KPAD + k] = lb;
}

// ---------------- MFMA GEMM: C[N x OUTC](f16) = dinv .* (A[N x 128] @ W) ----------------
template <int OUTC, typename AT>
__global__ __launch_bounds__(256, 2) void k_gemm_mfma(const AT* __restrict__ A,
                                                      const __bf16* __restrict__ WT,
                                                      const float* __restrict__ dinv,
                                                      f16* __restrict__ C, int N) {
    __shared__ __bf16 lds[2 * OUTC * KPAD];
    const int t = threadIdx.x;
    const int n16 = (2 * OUTC * KPAD * 2) / 16;
    for (int i = t; i < n16; i += 256)
        ((float4*)lds)[i] = ((const float4*)WT)[i];

    const int lane = t & 63;
    const int wv = t >> 6;
    const int c = lane & 15;
    const int hq = lane >> 4;
    const int rowbase = blockIdx.x * 128 + wv * 32;

    bf16x8 ahi[2][4], alo[2][4];
    #pragma unroll
    for (int rt = 0; rt < 2; ++rt) {
        int ar = rowbase + rt * 16 + c;
        if (ar > N - 1) ar = N - 1;
        const AT* ap = A + (size_t)ar * 128 + hq * 8;
        #pragma unroll
        for (int ks = 0; ks < 4; ++ks) {
            float v[8];
            if constexpr (sizeof(AT) == 4) {
                float4 p = *(const float4*)(ap + ks * 32);
                float4 q = *(const float4*)(ap + ks * 32 + 4);
                v[0] = p.x; v[1] = p.y; v[2] = p.z; v[3] = p.w;
                v[4] = q.x; v[5] = q.y; v[6] = q.z; v[7] = q.w;
            } else {
                f16x8 r = *(const f16x8*)(ap + ks * 32);
                #pragma unroll
                for (int j = 0; j < 8; ++j) v[j] = (float)r[j];
            }
            #pragma unroll
            for (int j = 0; j < 8; ++j) {
                __bf16 hb = (__bf16)v[j];
                ahi[rt][ks][j] = hb;
                alo[rt][ks][j] = (__bf16)(v[j] - (float)hb);
            }
        }
    }
    // per-lane dinv for this lane's 8 output rows (independent of ct)
    float di[2][4];
    #pragma unroll
    for (int rt = 0; rt < 2; ++rt)
        #pragma unroll
        for (int r = 0; r < 4; ++r) {
            int row = rowbase + rt * 16 + hq * 4 + r;
            di[rt][r] = (row < N) ? dinv[row] : 0.f;
        }
    __syncthreads();

    #pragma unroll
    for (int ct = 0; ct < OUTC / 16; ++ct) {
        const __bf16* bp = &lds[(ct * 16 + c) * KPAD + hq * 8];
        bf16x8 bhi[4], blo[4];
        #pragma unroll
        for (int ks = 0; ks < 4; ++ks) {
            bhi[ks] = *reinterpret_cast<const bf16x8*>(bp + ks * 32);
            blo[ks] = *reinterpret_cast<const bf16x8*>(bp + OUTC * KPAD + ks * 32);
        }
        f32x4 acc0 = {0.f, 0.f, 0.f, 0.f};
        f32x4 acc1 = {0.f, 0.f, 0.f, 0.f};
        #pragma unroll
        for (int ks = 0; ks < 4; ++ks) {
            acc0 = __builtin_amdgcn_mfma_f32_16x16x32_bf16(ahi[0][ks], bhi[ks], acc0, 0, 0, 0);
            acc1 = __builtin_amdgcn_mfma_f32_16x16x32_bf16(ahi[1][ks], bhi[ks], acc1, 0, 0, 0);
            acc0 = __builtin_amdgcn_mfma_f32_16x16x32_bf16(alo[0][ks], bhi[ks], acc0, 0, 0, 0);
            acc1 = __builtin_amdgcn_mfma_f32_16x16x32_bf16(alo[1][ks], bhi[ks], acc1, 0, 0, 0);
            acc0 = __builtin_amdgcn_mfma_f32_16x16x32_bf16(ahi[0][ks], blo[ks], acc0, 0, 0, 0);
            acc1 = __builtin_amdgcn_mfma_f32_16x16x32_bf16(ahi[1][ks], blo[ks], acc1, 0, 0, 0);
        }
        const int col = ct * 16 + c;
        #pragma unroll
        for (int rt = 0; rt < 2; ++rt) {
            f32x4 a = rt ? acc1 : acc0;
            int row0 = rowbase + rt * 16 + hq * 4;
            #pragma unroll
            for (int r = 0; r < 4; ++r) {
                int row = row0 + r;
                if (row < N) C[(size_t)row * OUTC + col] = (f16)(a[r] * di[rt][r]);
            }
        }
    }
}

// ---------------- aggregation + LayerNorm + ReLU (128 cols f16, 1 wave/node) ----------------
// h is pre-scaled by dinv (hs). agg = dv * (hs_v + sum_u hs_u) + bias, then LN+ReLU.
__global__ __launch_bounds__(256) void k_agg_ln(const f16* __restrict__ h,
                                                const int* __restrict__ rowptr,
                                                const int* __restrict__ adj,
                                                const float* __restrict__ dinv,
                                                const float* __restrict__ bias,
                                                const float* __restrict__ g,
                                                const float* __restrict__ bn,
                                                f16* __restrict__ out, int N) {
    int lane = threadIdx.x & 63;
    int v = rfl(blockIdx.x * 4 + (threadIdx.x >> 6));
    if (v >= N) return;
    int c = lane * 2;
    float dv = rflf(dinv[v]);
    f16x2 hv = *(const f16x2*)&h[(size_t)v * 128 + c];
    float ax = (float)hv[0];
    float ay = (float)hv[1];
    int e0 = rfl(rowptr[v]);
    int e1 = rfl(rowptr[v + 1]);
    int e = e0;
    for (; e + 8 <= e1; e += 8) {
        const f16* rp[8];
        #pragma unroll
        for (int i = 0; i < 8; i++) rp[i] = h + (size_t)rfl(adj[e + i]) * 128;
        f16x2 hh[8];
        #pragma unroll
        for (int i = 0; i < 8; i++) hh[i] = *(const f16x2*)&rp[i][c];
        #pragma unroll
        for (int i = 0; i < 8; i++) { ax += (float)hh[i][0]; ay += (float)hh[i][1]; }
    }
    for (; e + 4 <= e1; e += 4) {
        const f16* rp[4];
        #pragma unroll
        for (int i = 0; i < 4; i++) rp[i] = h + (size_t)rfl(adj[e + i]) * 128;
        f16x2 hh[4];
        #pragma unroll
        for (int i = 0; i < 4; i++) hh[i] = *(const f16x2*)&rp[i][c];
        #pragma unroll
        for (int i = 0; i < 4; i++) { ax += (float)hh[i][0]; ay += (float)hh[i][1]; }
    }
    for (; e < e1; e++) {
        const f16* rp = h + (size_t)rfl(adj[e]) * 128;
        f16x2 hu = *(const f16x2*)&rp[c];
        ax += (float)hu[0];
        ay += (float)hu[1];
    }
    float2 bb = *(const float2*)&bias[c];
    float px = fmaf(dv, ax, bb.x);
    float py = fmaf(dv, ay, bb.y);
    float s = px + py;
    #pragma unroll
    for (int m = 32; m >= 1; m >>= 1) s += __shfl_xor(s, m);
    float mu = s * (1.0f / 128.0f);
    float dx = px - mu, dy = py - mu;
    float vs = dx * dx + dy * dy;
    #pragma unroll
    for (int m = 32; m >= 1; m >>= 1) vs += __shfl_xor(vs, m);
    float rs = rsqrtf(vs * (1.0f / 128.0f) + EPS);
    float2 gg = *(const float2*)&g[c];
    float2 bnv = *(const float2*)&bn[c];
    float ox = fmaxf(dx * rs * gg.x + bnv.x, 0.0f);
    float oy = fmaxf(dy * rs * gg.y + bnv.y, 0.0f);
    f16x2 o;
    o[0] = (f16)ox;
    o[1] = (f16)oy;
    *(f16x2*)&out[(size_t)v * 128 + c] = o;
}

// ---------------- aggregation + bias (64 cols f16 in, f32 out; 1 col/lane) ----------------
__global__ __launch_bounds__(256) void k_agg_out(const f16* __restrict__ h,
                                                 const int* __restrict__ rowptr,
                                                 const int* __restrict__ adj,
                                                 const float* __restrict__ dinv,
                                                 const float* __restrict__ bias,
                                                 float* __restrict__ out, int N) {
    int lane = threadIdx.x & 63;
    int v = rfl(blockIdx.x * 4 + (threadIdx.x >> 6));
    if (v >= N) return;
    float dv = rflf(dinv[v]);
    float acc = (float)h[(size_t)v * 64 + lane];
    int e0 = rfl(rowptr[v]);
    int e1 = rfl(rowptr[v + 1]);
    int e = e0;
    for (; e + 8 <= e1; e += 8) {
        const f16* rp[8];
        #pragma unroll
        for (int i = 0; i < 8; i++) rp[i] = h + (size_t)rfl(adj[e + i]) * 64;
        f16 hh[8];
        #pragma unroll
        for (int i = 0; i < 8; i++) hh[i] = rp[i][lane];
        #pragma unroll
        for (int i = 0; i < 8; i++) acc += (float)hh[i];
    }
    for (; e + 4 <= e1; e += 4) {
        const f16* rp[4];
        #pragma unroll
        for (int i = 0; i < 4; i++) rp[i] = h + (size_t)rfl(adj[e + i]) * 64;
        f16 hh[4];
        #pragma unroll
        for (int i = 0; i < 4; i++) hh[i] = rp[i][lane];
        #pragma unroll
        for (int i = 0; i < 4; i++) acc += (float)hh[i];
    }
    for (; e < e1; e++) {
        acc += (float)h[(size_t)rfl(adj[e]) * 64 + lane];
    }
    out[(size_t)v * 64 + lane] = fmaf(dv, acc, bias[lane]);
}

extern "C" void kernel_launch(void* const* d_in, const int* in_sizes, int n_in,
                              void* d_out, int out_size, void* d_ws, size_t ws_size,
                              hipStream_t stream) {
    const float* x    = (const float*)d_in[0];
    const void*  eidx = d_in[1];
    const float* W0 = (const float*)d_in[2];
    const float* b0 = (const float*)d_in[3];
    const float* W1 = (const float*)d_in[4];
    const float* b1 = (const float*)d_in[5];
    const float* W2 = (const float*)d_in[6];
    const float* b2 = (const float*)d_in[7];
    const float* g0 = (const float*)d_in[8];
    const float* bn0 = (const float*)d_in[9];
    const float* g1 = (const float*)d_in[10];
    const float* bn1 = (const float*)d_in[11];

    int N = in_sizes[0] / 128;
    int E = in_sizes[1] / 2;

    char* p = (char*)d_ws;
    auto alloc = [&](size_t bytes) {
        char* r = p;
        p += (bytes + 255) & ~(size_t)255;
        return r;
    };
    int*   src32  = (int*)alloc((size_t)E * 4);
    int*   dst32  = (int*)alloc((size_t)E * 4);
    int*   cnt    = (int*)alloc((size_t)N * 4);
    int*   rowptr = (int*)alloc(((size_t)N + 1) * 4);
    int*   cursor = (int*)alloc((size_t)N * 4);
    float* dinv   = (float*)alloc((size_t)N * 4);
    int*   adj    = (int*)alloc((size_t)E * 4);
    int*   bsums  = (int*)alloc(4096);
    __bf16* wt0   = (__bf16*)alloc(2 * 128 * KPAD * 2);
    __bf16* wt1   = (__bf16*)alloc(2 * 128 * KPAD * 2);
    __bf16* wt2   = (__bf16*)alloc(2 * 64 * KPAD * 2);
    f16*   bufA   = (f16*)alloc((size_t)N * 128 * 2);
    f16*   bufB   = (f16*)alloc((size_t)N * 128 * 2);

    int eb = (E + 255) / 256;
    int nb = (N + 255) / 256;
    int nscan = (N + SCAN_CHUNK - 1) / SCAN_CHUNK;

    hipMemsetAsync(cnt, 0, (size_t)N * 4, stream);
    k_wconv<<<dim3(64, 3), 256, 0, stream>>>(W0, W1, W2, wt0, wt1, wt2);
    k_convert_count<<<eb, 256, 0, stream>>>(eidx, src32, dst32, cnt, E);
    k_scan1<<<nscan, 256, 0, stream>>>(cnt, rowptr, bsums, N);
    k_scan2<<<1, 64, 0, stream>>>(bsums, nscan);
    k_scan3_prep<<<nb, 256, 0, stream>>>(rowptr, bsums, cnt, cursor, dinv, N, E);
    k_fill<<<eb, 256, 0, stream>>>(src32, dst32, cursor, adj, E);

    int gemmb = (N + 127) / 128;
    int aggb = (N + 3) / 4;

    k_gemm_mfma<128, float><<<gemmb, 256, 0, stream>>>(x, wt0, dinv, bufA, N);
    k_agg_ln<<<aggb, 256, 0, stream>>>(bufA, rowptr, adj, dinv, b0, g0, bn0, bufB, N);
    k_gemm_mfma<128, f16><<<gemmb, 256, 0, stream>>>(bufB, wt1, dinv, bufA, N);
    k_agg_ln<<<aggb, 256, 0, stream>>>(bufA, rowptr, adj, dinv, b1, g1, bn1, bufB, N);
    k_gemm_mfma<64, f16><<<gemmb, 256, 0, stream>>>(bufB, wt2, dinv, bufA, N);
    k_agg_out<<<aggb, 256, 0, stream>>>(bufA, rowptr, adj, dinv, b2, (float*)d_out, N);
}